// Round 1
// baseline (15425.015 us; speedup 1.0000x reference)
//
#include <hip/hip_runtime.h>
#include <hip/hip_bf16.h>

// ---------------------------------------------------------------------------
// GCN stack: 3 graphs x 3 layers (256->256->128->64), final scalar = sum/64.
// Math trick: with h' = (x@W) * dis[row],
//   out[i] = relu( dis[i] * (h'[i] + sum_{e: dst=i} h'[src[e]]) + b )
// so the per-edge norm product disappears; scatter is a plain segment-sum.
// ---------------------------------------------------------------------------

__global__ __launch_bounds__(64) void zero_out_k(float* out) {
    if (threadIdx.x == 0 && blockIdx.x == 0) out[0] = 0.0f;
}

__global__ __launch_bounds__(256) void init_deg_k(float* deg, int n) {
    int i = blockIdx.x * 256 + threadIdx.x;
    if (i < n) deg[i] = 1.0f;   // self-loop weight
}

__global__ __launch_bounds__(256) void count_deg_k(float* deg, const int* __restrict__ dst, int e) {
    int i = blockIdx.x * 256 + threadIdx.x;
    if (i < e) atomicAdd(&deg[dst[i]], 1.0f);
}

__global__ __launch_bounds__(256) void rsqrt_k(float* deg, int n) {
    int i = blockIdx.x * 256 + threadIdx.x;
    if (i < n) deg[i] = rsqrtf(deg[i]);
}

// H[i][n] = (sum_k X[i][k]*W[k][n]) * dis[i];  ACC = copy of H (self-loop init)
// 64x64 tile, BK=16, 256 threads, 4x4 micro-tile per thread.
__global__ __launch_bounds__(256) void gemm_scale_copy_k(
    const float* __restrict__ X, const float* __restrict__ W,
    const float* __restrict__ dis, float* __restrict__ H, float* __restrict__ ACC,
    int M, int K, int N)
{
    __shared__ float As[16][65];   // As[k][m], padded to break 4-way store conflict
    __shared__ float Bs[16][64];   // Bs[k][n]

    const int tid = threadIdx.x;
    const int tx = tid & 15;          // output col group
    const int ty = tid >> 4;          // output row group
    const int block_row = blockIdx.y * 64;
    const int block_col = blockIdx.x * 64;

    // A tile loader mapping: thread -> (row 0..63, k-chunk of 4)
    const int a_row  = tid >> 2;
    const int a_col4 = (tid & 3) << 2;
    // B tile loader mapping: thread -> (k-row 0..15, col-chunk of 4)
    const int b_row  = tid >> 4;
    const int b_col4 = (tid & 15) << 2;

    float acc[4][4] = {};

    for (int k0 = 0; k0 < K; k0 += 16) {
        float4 av = make_float4(0.f, 0.f, 0.f, 0.f);
        int gr = block_row + a_row;
        if (gr < M) av = *(const float4*)(X + (long)gr * K + (k0 + a_col4));
        As[a_col4 + 0][a_row] = av.x;
        As[a_col4 + 1][a_row] = av.y;
        As[a_col4 + 2][a_row] = av.z;
        As[a_col4 + 3][a_row] = av.w;

        float4 bv = *(const float4*)(W + (long)(k0 + b_row) * N + block_col + b_col4);
        *(float4*)&Bs[b_row][b_col4] = bv;

        __syncthreads();
        #pragma unroll
        for (int k = 0; k < 16; ++k) {
            float a[4], b[4];
            #pragma unroll
            for (int i = 0; i < 4; ++i) a[i] = As[k][ty * 4 + i];
            #pragma unroll
            for (int j = 0; j < 4; ++j) b[j] = Bs[k][tx * 4 + j];
            #pragma unroll
            for (int i = 0; i < 4; ++i)
                #pragma unroll
                for (int j = 0; j < 4; ++j)
                    acc[i][j] = fmaf(a[i], b[j], acc[i][j]);
        }
        __syncthreads();
    }

    #pragma unroll
    for (int i = 0; i < 4; ++i) {
        int r = block_row + ty * 4 + i;
        if (r >= M) continue;
        float s = dis[r];
        float4 v = make_float4(acc[i][0] * s, acc[i][1] * s, acc[i][2] * s, acc[i][3] * s);
        long off = (long)r * N + block_col + tx * 4;
        *(float4*)(H + off)   = v;
        *(float4*)(ACC + off) = v;
    }
}

// ACC[dst] += H[src] over all edges. One thread per (edge, 4-feature chunk).
template<int F>
__global__ __launch_bounds__(256) void scatter_k(
    const float* __restrict__ H, float* __restrict__ ACC,
    const int* __restrict__ src, const int* __restrict__ dst, int E)
{
    constexpr int V = F / 4;                    // power of 2: 64/32/16
    long gid = (long)blockIdx.x * 256 + threadIdx.x;
    if (gid >= (long)E * V) return;
    int e = (int)(gid / V);
    int c = (int)(gid & (V - 1));
    int s = src[e];
    int d = dst[e];
    float4 v = *(const float4*)(H + (long)s * F + c * 4);
    float* p = ACC + (long)d * F + c * 4;
    atomicAdd(p + 0, v.x);
    atomicAdd(p + 1, v.y);
    atomicAdd(p + 2, v.z);
    atomicAdd(p + 3, v.w);
}

// In-place: ACC[i][f] = relu(dis[i]*ACC[i][f] + b[f])
template<int F>
__global__ __launch_bounds__(256) void finalize_k(
    float* __restrict__ ACC, const float* __restrict__ dis,
    const float* __restrict__ bias, int n)
{
    constexpr int V = F / 4;
    long gid = (long)blockIdx.x * 256 + threadIdx.x;
    if (gid >= (long)n * V) return;
    int row = (int)(gid / V);
    int c   = (int)(gid & (V - 1));
    float s = dis[row];
    float4 v = *(float4*)(ACC + (long)row * F + c * 4);
    float4 bb = *(const float4*)(bias + c * 4);
    v.x = fmaxf(fmaf(s, v.x, bb.x), 0.f);
    v.y = fmaxf(fmaf(s, v.y, bb.y), 0.f);
    v.z = fmaxf(fmaf(s, v.z, bb.z), 0.f);
    v.w = fmaxf(fmaf(s, v.w, bb.w), 0.f);
    *(float4*)(ACC + (long)row * F + c * 4) = v;
}

// Layer-3 finalize fused with global reduction: out += sum(relu(...))/64
__global__ __launch_bounds__(256) void finalize_reduce_k(
    const float* __restrict__ ACC, const float* __restrict__ dis,
    const float* __restrict__ bias, int n, float* __restrict__ out)
{
    long gid = (long)blockIdx.x * 256 + threadIdx.x;
    float val = 0.f;
    if (gid < (long)n * 64) {
        int row = (int)(gid >> 6);
        int c   = (int)(gid & 63);
        val = fmaxf(fmaf(dis[row], ACC[gid], bias[c]), 0.f);
    }
    #pragma unroll
    for (int off = 32; off > 0; off >>= 1) val += __shfl_down(val, off);
    __shared__ float wsum[4];
    int lane = threadIdx.x & 63, wid = threadIdx.x >> 6;
    if (lane == 0) wsum[wid] = val;
    __syncthreads();
    if (threadIdx.x == 0) {
        float s = (wsum[0] + wsum[1] + wsum[2] + wsum[3]) * (1.0f / 64.0f);
        atomicAdd(out, s);
    }
}

extern "C" void kernel_launch(void* const* d_in, const int* in_sizes, int n_in,
                              void* d_out, int out_size, void* d_ws, size_t ws_size,
                              hipStream_t stream) {
    const float* X[3]  = {(const float*)d_in[0], (const float*)d_in[1], (const float*)d_in[2]};
    const int*   EI[3] = {(const int*)d_in[3], (const int*)d_in[4], (const int*)d_in[5]};
    const float* W1 = (const float*)d_in[6];
    const float* b1 = (const float*)d_in[7];
    const float* W2 = (const float*)d_in[8];
    const float* b2 = (const float*)d_in[9];
    const float* W3 = (const float*)d_in[10];
    const float* b3 = (const float*)d_in[11];
    float* out = (float*)d_out;

    const int Nn = in_sizes[0] / 256;   // 50000
    const int E  = in_sizes[3] / 2;     // 800000

    // Workspace layout (floats): dis[Nn] | H[Nn*256] | A1[Nn*256] | A2[Nn*256]
    float* ws  = (float*)d_ws;
    float* dis = ws;
    float* H   = ws + 50048;
    float* A1  = H  + (size_t)Nn * 256;
    float* A2  = A1 + (size_t)Nn * 256;

    zero_out_k<<<1, 64, 0, stream>>>(out);

    const int nb_n = (Nn + 255) / 256;
    const int nb_e = (E + 255) / 256;

    for (int g = 0; g < 3; ++g) {
        const int* src = EI[g];
        const int* dst = EI[g] + E;

        init_deg_k<<<nb_n, 256, 0, stream>>>(dis, Nn);
        count_deg_k<<<nb_e, 256, 0, stream>>>(dis, dst, E);
        rsqrt_k<<<nb_n, 256, 0, stream>>>(dis, Nn);

        // ---- Layer 1: [Nn,256] @ [256,256] ----
        {
            dim3 grid(256 / 64, (Nn + 63) / 64);
            gemm_scale_copy_k<<<grid, 256, 0, stream>>>(X[g], W1, dis, H, A1, Nn, 256, 256);
            long tot = (long)E * 64;
            scatter_k<256><<<(int)((tot + 255) / 256), 256, 0, stream>>>(H, A1, src, dst, E);
            long ft = (long)Nn * 64;
            finalize_k<256><<<(int)((ft + 255) / 256), 256, 0, stream>>>(A1, dis, b1, Nn);
        }
        // ---- Layer 2: [Nn,256] @ [256,128] ----
        {
            dim3 grid(128 / 64, (Nn + 63) / 64);
            gemm_scale_copy_k<<<grid, 256, 0, stream>>>(A1, W2, dis, H, A2, Nn, 256, 128);
            long tot = (long)E * 32;
            scatter_k<128><<<(int)((tot + 255) / 256), 256, 0, stream>>>(H, A2, src, dst, E);
            long ft = (long)Nn * 32;
            finalize_k<128><<<(int)((ft + 255) / 256), 256, 0, stream>>>(A2, dis, b2, Nn);
        }
        // ---- Layer 3: [Nn,128] @ [128,64], fused reduce ----
        {
            dim3 grid(64 / 64, (Nn + 63) / 64);
            gemm_scale_copy_k<<<grid, 256, 0, stream>>>(A2, W3, dis, H, A1, Nn, 128, 64);
            long tot = (long)E * 16;
            scatter_k<64><<<(int)((tot + 255) / 256), 256, 0, stream>>>(H, A1, src, dst, E);
            long ft = (long)Nn * 64;
            finalize_reduce_k<<<(int)((ft + 255) / 256), 256, 0, stream>>>(A1, dis, b3, Nn, out);
        }
    }
}

// Round 2
// 1770.219 us; speedup vs baseline: 8.7136x; 8.7136x over previous
//
#include <hip/hip_runtime.h>
#include <hip/hip_bf16.h>

// ---------------------------------------------------------------------------
// GCN stack: 3 graphs x 3 layers (256->256->128->64), final scalar = sum/64.
// Math: with h' = (x@W) * dis[row],
//   out[i] = relu( dis[i] * (h'[i] + sum_{e: dst=i} h'[src[e]]) + b )
// R2: CSR-by-dst + gather (no feature atomics). Atomic scatter wrote 3.2 GB
// to HBM per layer-1 dispatch (write-through RMW); gather reads neighbor rows
// from L3-resident H instead.
// ---------------------------------------------------------------------------

__global__ __launch_bounds__(64) void zero_out_k(float* out) {
    if (threadIdx.x == 0 && blockIdx.x == 0) out[0] = 0.0f;
}

__global__ __launch_bounds__(256) void zero_ints_k(int* p, int n) {
    int i = blockIdx.x * 256 + threadIdx.x;
    if (i < n) p[i] = 0;
}

__global__ __launch_bounds__(256) void count_deg_k(int* cnt, const int* __restrict__ dst, int e) {
    int i = blockIdx.x * 256 + threadIdx.x;
    if (i < e) atomicAdd(&cnt[dst[i]], 1);
}

__global__ __launch_bounds__(256) void dis_k(const int* __restrict__ cnt, float* dis, int n) {
    int i = blockIdx.x * 256 + threadIdx.x;
    if (i < n) dis[i] = rsqrtf((float)cnt[i] + 1.0f);
}

// Single-block exclusive scan (wave-shfl based), n up to ~hundreds of K.
__global__ __launch_bounds__(1024) void scan_k(const int* __restrict__ cnt,
                                               int* __restrict__ row_start, int n) {
    __shared__ int wsum[16];
    __shared__ int carry_s;
    if (threadIdx.x == 0) carry_s = 0;
    __syncthreads();
    const int lane = threadIdx.x & 63;
    const int wid  = threadIdx.x >> 6;
    for (int base = 0; base < n; base += 1024) {
        int i = base + threadIdx.x;
        int v = (i < n) ? cnt[i] : 0;
        // inclusive scan within wave
        int x = v;
        #pragma unroll
        for (int off = 1; off < 64; off <<= 1) {
            int t = __shfl_up(x, off);
            if (lane >= off) x += t;
        }
        if (lane == 63) wsum[wid] = x;
        __syncthreads();
        if (wid == 0) {
            int w = (lane < 16) ? wsum[lane] : 0;
            #pragma unroll
            for (int off = 1; off < 16; off <<= 1) {
                int t = __shfl_up(w, off);
                if (lane >= off) w += t;
            }
            if (lane < 16) wsum[lane] = w;   // inclusive wave sums
        }
        __syncthreads();
        int wave_excl = (wid == 0) ? 0 : wsum[wid - 1];
        int excl = wave_excl + x - v;
        int carry = carry_s;
        if (i < n) row_start[i] = carry + excl;
        int total = wsum[15];
        __syncthreads();
        if (threadIdx.x == 0) carry_s = carry + total;
        __syncthreads();
    }
}

__global__ __launch_bounds__(256) void fill_csr_k(
    const int* __restrict__ src, const int* __restrict__ dst, int E,
    const int* __restrict__ row_start, int* __restrict__ fill, int* __restrict__ csr) {
    int e = blockIdx.x * 256 + threadIdx.x;
    if (e < E) {
        int d = dst[e];
        int p = atomicAdd(&fill[d], 1);
        csr[row_start[d] + p] = src[e];
    }
}

// H[i][n] = (sum_k X[i][k]*W[k][n]) * dis[i]
// 64x64 tile, BK=16, 256 threads, 4x4 micro-tile per thread.
__global__ __launch_bounds__(256) void gemm_scale_k(
    const float* __restrict__ X, const float* __restrict__ W,
    const float* __restrict__ dis, float* __restrict__ H,
    int M, int K, int N)
{
    __shared__ float As[16][65];
    __shared__ float Bs[16][64];

    const int tid = threadIdx.x;
    const int tx = tid & 15;
    const int ty = tid >> 4;
    const int block_row = blockIdx.y * 64;
    const int block_col = blockIdx.x * 64;

    const int a_row  = tid >> 2;
    const int a_col4 = (tid & 3) << 2;
    const int b_row  = tid >> 4;
    const int b_col4 = (tid & 15) << 2;

    float acc[4][4] = {};

    for (int k0 = 0; k0 < K; k0 += 16) {
        float4 av = make_float4(0.f, 0.f, 0.f, 0.f);
        int gr = block_row + a_row;
        if (gr < M) av = *(const float4*)(X + (long)gr * K + (k0 + a_col4));
        As[a_col4 + 0][a_row] = av.x;
        As[a_col4 + 1][a_row] = av.y;
        As[a_col4 + 2][a_row] = av.z;
        As[a_col4 + 3][a_row] = av.w;

        float4 bv = *(const float4*)(W + (long)(k0 + b_row) * N + block_col + b_col4);
        *(float4*)&Bs[b_row][b_col4] = bv;

        __syncthreads();
        #pragma unroll
        for (int k = 0; k < 16; ++k) {
            float a[4], b[4];
            #pragma unroll
            for (int i = 0; i < 4; ++i) a[i] = As[k][ty * 4 + i];
            #pragma unroll
            for (int j = 0; j < 4; ++j) b[j] = Bs[k][tx * 4 + j];
            #pragma unroll
            for (int i = 0; i < 4; ++i)
                #pragma unroll
                for (int j = 0; j < 4; ++j)
                    acc[i][j] = fmaf(a[i], b[j], acc[i][j]);
        }
        __syncthreads();
    }

    #pragma unroll
    for (int i = 0; i < 4; ++i) {
        int r = block_row + ty * 4 + i;
        if (r >= M) continue;
        float s = dis[r];
        float4 v = make_float4(acc[i][0] * s, acc[i][1] * s, acc[i][2] * s, acc[i][3] * s);
        *(float4*)(H + (long)r * N + block_col + tx * 4) = v;
    }
}

// OUT[i] = relu(dis[i] * (H[i] + sum_{s in nbrs(i)} H[s]) + b)
// F/4 lanes per node; 256-thread block handles 1024/F nodes.
template<int F>
__global__ __launch_bounds__(256) void gather_relu_k(
    const float* __restrict__ H, float* __restrict__ OUT,
    const int* __restrict__ row_start, const int* __restrict__ cnt,
    const int* __restrict__ csr, const float* __restrict__ dis,
    const float* __restrict__ bias, int n)
{
    constexpr int L = F / 4;
    constexpr int NPB = 256 / L;
    int node = blockIdx.x * NPB + threadIdx.x / L;
    if (node >= n) return;
    int c = (threadIdx.x % L) * 4;

    float4 acc = *(const float4*)(H + (long)node * F + c);   // self-loop
    int base = row_start[node];
    int deg  = cnt[node];
    int k = 0;
    for (; k + 1 < deg; k += 2) {
        int s0 = csr[base + k];
        int s1 = csr[base + k + 1];
        float4 v0 = *(const float4*)(H + (long)s0 * F + c);
        float4 v1 = *(const float4*)(H + (long)s1 * F + c);
        acc.x += v0.x + v1.x; acc.y += v0.y + v1.y;
        acc.z += v0.z + v1.z; acc.w += v0.w + v1.w;
    }
    if (k < deg) {
        int s0 = csr[base + k];
        float4 v0 = *(const float4*)(H + (long)s0 * F + c);
        acc.x += v0.x; acc.y += v0.y; acc.z += v0.z; acc.w += v0.w;
    }
    float di = dis[node];
    float4 bb = *(const float4*)(bias + c);
    acc.x = fmaxf(fmaf(di, acc.x, bb.x), 0.f);
    acc.y = fmaxf(fmaf(di, acc.y, bb.y), 0.f);
    acc.z = fmaxf(fmaf(di, acc.z, bb.z), 0.f);
    acc.w = fmaxf(fmaf(di, acc.w, bb.w), 0.f);
    *(float4*)(OUT + (long)node * F + c) = acc;
}

// Layer-3 variant: instead of storing, reduce sum(relu)/64 into out.
__global__ __launch_bounds__(256) void gather_relu_reduce_k(
    const float* __restrict__ H,
    const int* __restrict__ row_start, const int* __restrict__ cnt,
    const int* __restrict__ csr, const float* __restrict__ dis,
    const float* __restrict__ bias, int n, float* __restrict__ out)
{
    constexpr int F = 64, L = 16, NPB = 16;
    int node = blockIdx.x * NPB + threadIdx.x / L;
    int c = (threadIdx.x % L) * 4;
    float val = 0.f;
    if (node < n) {
        float4 acc = *(const float4*)(H + (long)node * F + c);
        int base = row_start[node];
        int deg  = cnt[node];
        int k = 0;
        for (; k + 1 < deg; k += 2) {
            int s0 = csr[base + k];
            int s1 = csr[base + k + 1];
            float4 v0 = *(const float4*)(H + (long)s0 * F + c);
            float4 v1 = *(const float4*)(H + (long)s1 * F + c);
            acc.x += v0.x + v1.x; acc.y += v0.y + v1.y;
            acc.z += v0.z + v1.z; acc.w += v0.w + v1.w;
        }
        if (k < deg) {
            int s0 = csr[base + k];
            float4 v0 = *(const float4*)(H + (long)s0 * F + c);
            acc.x += v0.x; acc.y += v0.y; acc.z += v0.z; acc.w += v0.w;
        }
        float di = dis[node];
        float4 bb = *(const float4*)(bias + c);
        val = fmaxf(fmaf(di, acc.x, bb.x), 0.f)
            + fmaxf(fmaf(di, acc.y, bb.y), 0.f)
            + fmaxf(fmaf(di, acc.z, bb.z), 0.f)
            + fmaxf(fmaf(di, acc.w, bb.w), 0.f);
    }
    #pragma unroll
    for (int off = 32; off > 0; off >>= 1) val += __shfl_down(val, off);
    __shared__ float wsum[4];
    int lane = threadIdx.x & 63, wid = threadIdx.x >> 6;
    if (lane == 0) wsum[wid] = val;
    __syncthreads();
    if (threadIdx.x == 0) {
        float s = (wsum[0] + wsum[1] + wsum[2] + wsum[3]) * (1.0f / 64.0f);
        atomicAdd(out, s);
    }
}

extern "C" void kernel_launch(void* const* d_in, const int* in_sizes, int n_in,
                              void* d_out, int out_size, void* d_ws, size_t ws_size,
                              hipStream_t stream) {
    const float* X[3]  = {(const float*)d_in[0], (const float*)d_in[1], (const float*)d_in[2]};
    const int*   EI[3] = {(const int*)d_in[3], (const int*)d_in[4], (const int*)d_in[5]};
    const float* W1 = (const float*)d_in[6];
    const float* b1 = (const float*)d_in[7];
    const float* W2 = (const float*)d_in[8];
    const float* b2 = (const float*)d_in[9];
    const float* W3 = (const float*)d_in[10];
    const float* b3 = (const float*)d_in[11];
    float* out = (float*)d_out;

    const int Nn = in_sizes[0] / 256;   // 50000
    const int E  = in_sizes[3] / 2;     // 800000

    // Workspace layout (4B elements):
    // A[Nn*256] | H[Nn*256] | dis[Nn] | cnt[Nn] | fill[Nn] | row_start[Nn+1] | csr[E]
    float* ws = (float*)d_ws;
    float* A   = ws;
    float* H   = A + (size_t)Nn * 256;
    float* dis = H + (size_t)Nn * 256;
    int* cnt       = (int*)(dis + Nn);
    int* fill      = cnt + Nn;
    int* row_start = fill + Nn;
    int* csr       = row_start + Nn + 1;

    zero_out_k<<<1, 64, 0, stream>>>(out);

    const int nb_n = (Nn + 255) / 256;
    const int nb_e = (E + 255) / 256;

    for (int g = 0; g < 3; ++g) {
        const int* src = EI[g];
        const int* dst = EI[g] + E;

        // --- CSR build (shared by all 3 layers of this graph) ---
        zero_ints_k<<<(2 * Nn + 255) / 256, 256, 0, stream>>>(cnt, 2 * Nn); // cnt+fill
        count_deg_k<<<nb_e, 256, 0, stream>>>(cnt, dst, E);
        dis_k<<<nb_n, 256, 0, stream>>>(cnt, dis, Nn);
        scan_k<<<1, 1024, 0, stream>>>(cnt, row_start, Nn);
        fill_csr_k<<<nb_e, 256, 0, stream>>>(src, dst, E, row_start, fill, csr);

        // ---- Layer 1: [Nn,256] @ [256,256] ----
        {
            dim3 grid(256 / 64, (Nn + 63) / 64);
            gemm_scale_k<<<grid, 256, 0, stream>>>(X[g], W1, dis, H, Nn, 256, 256);
            gather_relu_k<256><<<(Nn + 3) / 4, 256, 0, stream>>>(
                H, A, row_start, cnt, csr, dis, b1, Nn);
        }
        // ---- Layer 2: [Nn,256] @ [256,128] ----
        {
            dim3 grid(128 / 64, (Nn + 63) / 64);
            gemm_scale_k<<<grid, 256, 0, stream>>>(A, W2, dis, H, Nn, 256, 128);
            gather_relu_k<128><<<(Nn + 7) / 8, 256, 0, stream>>>(
                H, A, row_start, cnt, csr, dis, b2, Nn);
        }
        // ---- Layer 3: [Nn,128] @ [128,64], fused scalar reduce ----
        {
            dim3 grid(64 / 64, (Nn + 63) / 64);
            gemm_scale_k<<<grid, 256, 0, stream>>>(A, W3, dis, H, Nn, 128, 64);
            gather_relu_reduce_k<<<(Nn + 15) / 16, 256, 0, stream>>>(
                H, row_start, cnt, csr, dis, b3, Nn, out);
        }
    }
}

// Round 3
// 1380.238 us; speedup vs baseline: 11.1756x; 1.2825x over previous
//
#include <hip/hip_runtime.h>
#include <hip/hip_bf16.h>

// ---------------------------------------------------------------------------
// GCN stack: 3 graphs x 3 layers (256->256->128->64), final scalar = sum/64.
// Math: with h' = (x@W) * dis[row],
//   out[i] = relu( dis[i] * (h'[i] + sum_{e: dst=i} h'[src[e]]) + b )
// R3: H stored as bf16 (halves gather-side bandwidth; fp32 GEMM accumulate,
// round only at epilogue). Multi-block scan replaces single-block scan.
// ---------------------------------------------------------------------------

typedef unsigned short ushort_t;
typedef unsigned int uint_t;

static __device__ __forceinline__ ushort_t f2bf(float f) {
    uint_t u = __float_as_uint(f);
    u += 0x7fffu + ((u >> 16) & 1u);   // round-to-nearest-even
    return (ushort_t)(u >> 16);
}

// Load 4 consecutive bf16 (8 bytes) and widen to float4.
static __device__ __forceinline__ float4 load_bf4(const ushort_t* p) {
    uint2 u = *(const uint2*)p;
    float4 f;
    f.x = __uint_as_float(u.x << 16);
    f.y = __uint_as_float(u.x & 0xffff0000u);
    f.z = __uint_as_float(u.y << 16);
    f.w = __uint_as_float(u.y & 0xffff0000u);
    return f;
}

__global__ __launch_bounds__(64) void zero_out_k(float* out) {
    if (threadIdx.x == 0 && blockIdx.x == 0) out[0] = 0.0f;
}

__global__ __launch_bounds__(256) void zero_ints_k(int* p, int n) {
    int i = blockIdx.x * 256 + threadIdx.x;
    if (i < n) p[i] = 0;
}

__global__ __launch_bounds__(256) void count_deg_k(int* cnt, const int* __restrict__ dst, int e) {
    int i = blockIdx.x * 256 + threadIdx.x;
    if (i < e) atomicAdd(&cnt[dst[i]], 1);
}

__global__ __launch_bounds__(256) void dis_k(const int* __restrict__ cnt, float* dis, int n) {
    int i = blockIdx.x * 256 + threadIdx.x;
    if (i < n) dis[i] = rsqrtf((float)cnt[i] + 1.0f);
}

// ---- 3-kernel exclusive scan over cnt[n] -> row_start[n] ----
// scan1: per-block (1024-elem chunk) sums
__global__ __launch_bounds__(256) void scan1_k(const int* __restrict__ cnt,
                                               int* __restrict__ block_sums, int n) {
    int base = blockIdx.x * 1024 + threadIdx.x * 4;
    int s = 0;
    #pragma unroll
    for (int j = 0; j < 4; ++j) { int i = base + j; if (i < n) s += cnt[i]; }
    #pragma unroll
    for (int off = 32; off > 0; off >>= 1) s += __shfl_down(s, off);
    __shared__ int wsum[4];
    int lane = threadIdx.x & 63, wid = threadIdx.x >> 6;
    if (lane == 0) wsum[wid] = s;
    __syncthreads();
    if (threadIdx.x == 0) block_sums[blockIdx.x] = wsum[0] + wsum[1] + wsum[2] + wsum[3];
}

// scan2: exclusive scan of up to 64 block sums (single wave)
__global__ __launch_bounds__(64) void scan2_k(const int* __restrict__ block_sums,
                                              int* __restrict__ block_offs, int nb) {
    int t = threadIdx.x;
    int v = (t < nb) ? block_sums[t] : 0;
    int x = v;
    #pragma unroll
    for (int off = 1; off < 64; off <<= 1) {
        int tt = __shfl_up(x, off);
        if (t >= off) x += tt;
    }
    if (t < nb) block_offs[t] = x - v;
}

// scan3: per-element exclusive prefix within chunk + block offset
__global__ __launch_bounds__(256) void scan3_k(const int* __restrict__ cnt,
                                               const int* __restrict__ block_offs,
                                               int* __restrict__ row_start, int n) {
    int base = blockIdx.x * 1024 + threadIdx.x * 4;
    int e[4];
    int s = 0;
    #pragma unroll
    for (int j = 0; j < 4; ++j) {
        int i = base + j;
        e[j] = (i < n) ? cnt[i] : 0;
        s += e[j];
    }
    int lane = threadIdx.x & 63, wid = threadIdx.x >> 6;
    int x = s;
    #pragma unroll
    for (int off = 1; off < 64; off <<= 1) {
        int t = __shfl_up(x, off);
        if (lane >= off) x += t;
    }
    __shared__ int wsum[4];
    if (lane == 63) wsum[wid] = x;
    __syncthreads();
    int wave_excl = 0;
    #pragma unroll
    for (int w = 0; w < 4; ++w) if (w < wid) wave_excl += wsum[w];
    int p = block_offs[blockIdx.x] + wave_excl + (x - s);
    #pragma unroll
    for (int j = 0; j < 4; ++j) {
        int i = base + j;
        if (i < n) row_start[i] = p;
        p += e[j];
    }
}

__global__ __launch_bounds__(256) void fill_csr_k(
    const int* __restrict__ src, const int* __restrict__ dst, int E,
    const int* __restrict__ row_start, int* __restrict__ fill, int* __restrict__ csr) {
    int e = blockIdx.x * 256 + threadIdx.x;
    if (e < E) {
        int d = dst[e];
        int p = atomicAdd(&fill[d], 1);
        csr[row_start[d] + p] = src[e];
    }
}

// H[i][n] = bf16( (sum_k X[i][k]*W[k][n]) * dis[i] )   (fp32 accumulate)
// 64x64 tile, BK=16, 256 threads, 4x4 micro-tile per thread.
__global__ __launch_bounds__(256) void gemm_scale_k(
    const float* __restrict__ X, const float* __restrict__ W,
    const float* __restrict__ dis, ushort_t* __restrict__ Hb,
    int M, int K, int N)
{
    __shared__ float As[16][65];
    __shared__ float Bs[16][64];

    const int tid = threadIdx.x;
    const int tx = tid & 15;
    const int ty = tid >> 4;
    const int block_row = blockIdx.y * 64;
    const int block_col = blockIdx.x * 64;

    const int a_row  = tid >> 2;
    const int a_col4 = (tid & 3) << 2;
    const int b_row  = tid >> 4;
    const int b_col4 = (tid & 15) << 2;

    float acc[4][4] = {};

    for (int k0 = 0; k0 < K; k0 += 16) {
        float4 av = make_float4(0.f, 0.f, 0.f, 0.f);
        int gr = block_row + a_row;
        if (gr < M) av = *(const float4*)(X + (long)gr * K + (k0 + a_col4));
        As[a_col4 + 0][a_row] = av.x;
        As[a_col4 + 1][a_row] = av.y;
        As[a_col4 + 2][a_row] = av.z;
        As[a_col4 + 3][a_row] = av.w;

        float4 bv = *(const float4*)(W + (long)(k0 + b_row) * N + block_col + b_col4);
        *(float4*)&Bs[b_row][b_col4] = bv;

        __syncthreads();
        #pragma unroll
        for (int k = 0; k < 16; ++k) {
            float a[4], b[4];
            #pragma unroll
            for (int i = 0; i < 4; ++i) a[i] = As[k][ty * 4 + i];
            #pragma unroll
            for (int j = 0; j < 4; ++j) b[j] = Bs[k][tx * 4 + j];
            #pragma unroll
            for (int i = 0; i < 4; ++i)
                #pragma unroll
                for (int j = 0; j < 4; ++j)
                    acc[i][j] = fmaf(a[i], b[j], acc[i][j]);
        }
        __syncthreads();
    }

    #pragma unroll
    for (int i = 0; i < 4; ++i) {
        int r = block_row + ty * 4 + i;
        if (r >= M) continue;
        float s = dis[r];
        ushort4 hv;
        hv.x = f2bf(acc[i][0] * s);
        hv.y = f2bf(acc[i][1] * s);
        hv.z = f2bf(acc[i][2] * s);
        hv.w = f2bf(acc[i][3] * s);
        *(ushort4*)(Hb + (long)r * N + block_col + tx * 4) = hv;
    }
}

// OUT[i] = relu(dis[i] * (H[i] + sum_{s in nbrs(i)} H[s]) + b), H in bf16.
// F/4 lanes per node; 256-thread block handles 1024/F nodes.
template<int F>
__global__ __launch_bounds__(256) void gather_relu_k(
    const ushort_t* __restrict__ Hb, float* __restrict__ OUT,
    const int* __restrict__ row_start, const int* __restrict__ cnt,
    const int* __restrict__ csr, const float* __restrict__ dis,
    const float* __restrict__ bias, int n)
{
    constexpr int L = F / 4;
    constexpr int NPB = 256 / L;
    int node = blockIdx.x * NPB + threadIdx.x / L;
    if (node >= n) return;
    int c = (threadIdx.x % L) * 4;

    float4 acc = load_bf4(Hb + (long)node * F + c);   // self-loop
    int base = row_start[node];
    int deg  = cnt[node];
    if constexpr (L == 64) {  // wave-uniform: scalarize for s_load of csr
        base = __builtin_amdgcn_readfirstlane(base);
        deg  = __builtin_amdgcn_readfirstlane(deg);
    }
    int k = 0;
    for (; k + 3 < deg; k += 4) {
        int s0 = csr[base + k];
        int s1 = csr[base + k + 1];
        int s2 = csr[base + k + 2];
        int s3 = csr[base + k + 3];
        float4 v0 = load_bf4(Hb + (long)s0 * F + c);
        float4 v1 = load_bf4(Hb + (long)s1 * F + c);
        float4 v2 = load_bf4(Hb + (long)s2 * F + c);
        float4 v3 = load_bf4(Hb + (long)s3 * F + c);
        acc.x += (v0.x + v1.x) + (v2.x + v3.x);
        acc.y += (v0.y + v1.y) + (v2.y + v3.y);
        acc.z += (v0.z + v1.z) + (v2.z + v3.z);
        acc.w += (v0.w + v1.w) + (v2.w + v3.w);
    }
    for (; k < deg; ++k) {
        int s0 = csr[base + k];
        float4 v0 = load_bf4(Hb + (long)s0 * F + c);
        acc.x += v0.x; acc.y += v0.y; acc.z += v0.z; acc.w += v0.w;
    }
    float di = dis[node];
    float4 bb = *(const float4*)(bias + c);
    acc.x = fmaxf(fmaf(di, acc.x, bb.x), 0.f);
    acc.y = fmaxf(fmaf(di, acc.y, bb.y), 0.f);
    acc.z = fmaxf(fmaf(di, acc.z, bb.z), 0.f);
    acc.w = fmaxf(fmaf(di, acc.w, bb.w), 0.f);
    *(float4*)(OUT + (long)node * F + c) = acc;
}

// Layer-3 variant: reduce sum(relu)/64 into out.
__global__ __launch_bounds__(256) void gather_relu_reduce_k(
    const ushort_t* __restrict__ Hb,
    const int* __restrict__ row_start, const int* __restrict__ cnt,
    const int* __restrict__ csr, const float* __restrict__ dis,
    const float* __restrict__ bias, int n, float* __restrict__ out)
{
    constexpr int F = 64, L = 16, NPB = 16;
    int node = blockIdx.x * NPB + threadIdx.x / L;
    int c = (threadIdx.x % L) * 4;
    float val = 0.f;
    if (node < n) {
        float4 acc = load_bf4(Hb + (long)node * F + c);
        int base = row_start[node];
        int deg  = cnt[node];
        int k = 0;
        for (; k + 3 < deg; k += 4) {
            int s0 = csr[base + k];
            int s1 = csr[base + k + 1];
            int s2 = csr[base + k + 2];
            int s3 = csr[base + k + 3];
            float4 v0 = load_bf4(Hb + (long)s0 * F + c);
            float4 v1 = load_bf4(Hb + (long)s1 * F + c);
            float4 v2 = load_bf4(Hb + (long)s2 * F + c);
            float4 v3 = load_bf4(Hb + (long)s3 * F + c);
            acc.x += (v0.x + v1.x) + (v2.x + v3.x);
            acc.y += (v0.y + v1.y) + (v2.y + v3.y);
            acc.z += (v0.z + v1.z) + (v2.z + v3.z);
            acc.w += (v0.w + v1.w) + (v2.w + v3.w);
        }
        for (; k < deg; ++k) {
            int s0 = csr[base + k];
            float4 v0 = load_bf4(Hb + (long)s0 * F + c);
            acc.x += v0.x; acc.y += v0.y; acc.z += v0.z; acc.w += v0.w;
        }
        float di = dis[node];
        float4 bb = *(const float4*)(bias + c);
        val = fmaxf(fmaf(di, acc.x, bb.x), 0.f)
            + fmaxf(fmaf(di, acc.y, bb.y), 0.f)
            + fmaxf(fmaf(di, acc.z, bb.z), 0.f)
            + fmaxf(fmaf(di, acc.w, bb.w), 0.f);
    }
    #pragma unroll
    for (int off = 32; off > 0; off >>= 1) val += __shfl_down(val, off);
    __shared__ float wsum[4];
    int lane = threadIdx.x & 63, wid = threadIdx.x >> 6;
    if (lane == 0) wsum[wid] = val;
    __syncthreads();
    if (threadIdx.x == 0) {
        float s = (wsum[0] + wsum[1] + wsum[2] + wsum[3]) * (1.0f / 64.0f);
        atomicAdd(out, s);
    }
}

extern "C" void kernel_launch(void* const* d_in, const int* in_sizes, int n_in,
                              void* d_out, int out_size, void* d_ws, size_t ws_size,
                              hipStream_t stream) {
    const float* X[3]  = {(const float*)d_in[0], (const float*)d_in[1], (const float*)d_in[2]};
    const int*   EI[3] = {(const int*)d_in[3], (const int*)d_in[4], (const int*)d_in[5]};
    const float* W1 = (const float*)d_in[6];
    const float* b1 = (const float*)d_in[7];
    const float* W2 = (const float*)d_in[8];
    const float* b2 = (const float*)d_in[9];
    const float* W3 = (const float*)d_in[10];
    const float* b3 = (const float*)d_in[11];
    float* out = (float*)d_out;

    const int Nn = in_sizes[0] / 256;   // 50000
    const int E  = in_sizes[3] / 2;     // 800000

    // Workspace layout:
    // A: fp32 [Nn*256] | Hb: bf16 [Nn*256] | dis: fp32 [Nn]
    // cnt[Nn] | fill[Nn] | row_start[Nn+1] | csr[E] | block_sums[64] | block_offs[64]
    float* A = (float*)d_ws;
    ushort_t* Hb = (ushort_t*)(A + (size_t)Nn * 256);
    float* dis = (float*)(Hb + (size_t)Nn * 256);
    int* cnt        = (int*)(dis + Nn);
    int* fill       = cnt + Nn;
    int* row_start  = fill + Nn;
    int* csr        = row_start + Nn + 1;
    int* block_sums = csr + E;
    int* block_offs = block_sums + 64;

    zero_out_k<<<1, 64, 0, stream>>>(out);

    const int nb_n = (Nn + 255) / 256;
    const int nb_e = (E + 255) / 256;
    const int nb_s = (Nn + 1023) / 1024;   // scan chunks (<= 64)

    for (int g = 0; g < 3; ++g) {
        const int* src = EI[g];
        const int* dst = EI[g] + E;

        // --- CSR build (shared by all 3 layers of this graph) ---
        zero_ints_k<<<(2 * Nn + 255) / 256, 256, 0, stream>>>(cnt, 2 * Nn); // cnt+fill
        count_deg_k<<<nb_e, 256, 0, stream>>>(cnt, dst, E);
        dis_k<<<nb_n, 256, 0, stream>>>(cnt, dis, Nn);
        scan1_k<<<nb_s, 256, 0, stream>>>(cnt, block_sums, Nn);
        scan2_k<<<1, 64, 0, stream>>>(block_sums, block_offs, nb_s);
        scan3_k<<<nb_s, 256, 0, stream>>>(cnt, block_offs, row_start, Nn);
        fill_csr_k<<<nb_e, 256, 0, stream>>>(src, dst, E, row_start, fill, csr);

        // ---- Layer 1: [Nn,256] @ [256,256] ----
        {
            dim3 grid(256 / 64, (Nn + 63) / 64);
            gemm_scale_k<<<grid, 256, 0, stream>>>(X[g], W1, dis, Hb, Nn, 256, 256);
            gather_relu_k<256><<<(Nn + 3) / 4, 256, 0, stream>>>(
                Hb, A, row_start, cnt, csr, dis, b1, Nn);
        }
        // ---- Layer 2: [Nn,256] @ [256,128] ----
        {
            dim3 grid(128 / 64, (Nn + 63) / 64);
            gemm_scale_k<<<grid, 256, 0, stream>>>(A, W2, dis, Hb, Nn, 256, 128);
            gather_relu_k<128><<<(Nn + 7) / 8, 256, 0, stream>>>(
                Hb, A, row_start, cnt, csr, dis, b2, Nn);
        }
        // ---- Layer 3: [Nn,128] @ [128,64], fused scalar reduce ----
        {
            dim3 grid(64 / 64, (Nn + 63) / 64);
            gemm_scale_k<<<grid, 256, 0, stream>>>(A, W3, dis, Hb, Nn, 128, 64);
            gather_relu_reduce_k<<<(Nn + 15) / 16, 256, 0, stream>>>(
                Hb, row_start, cnt, csr, dis, b3, Nn, out);
        }
    }
}

// Round 4
// 1071.890 us; speedup vs baseline: 14.3905x; 1.2877x over previous
//
#include <hip/hip_runtime.h>
#include <hip/hip_bf16.h>

// ---------------------------------------------------------------------------
// GCN stack: 3 graphs x 3 layers (256->256->128->64), final scalar = sum/64.
// Math: with h' = (x@W) * dis[row],
//   out[i] = relu( dis[i] * (h'[i] + sum_{e: dst=i} h'[src[e]]) + b )
// R4: all GEMMs on bf16 MFMA (16x16x32). Whole intermediate chain is bf16:
// X converted during staging; gather outputs bf16; weights pre-transposed
// to Wt[N,K] bf16 once per call so B stages identically to A.
// ---------------------------------------------------------------------------

typedef unsigned short ushort_t;
typedef unsigned int uint_t;
typedef __attribute__((ext_vector_type(8))) short v8s;   // 8 bf16 (4 VGPRs)
typedef __attribute__((ext_vector_type(4))) float v4f;   // MFMA accum

static __device__ __forceinline__ ushort_t f2bf(float f) {
    uint_t u = __float_as_uint(f);
    u += 0x7fffu + ((u >> 16) & 1u);   // round-to-nearest-even
    return (ushort_t)(u >> 16);
}
static __device__ __forceinline__ uint_t pack2(float a, float b) {
    return (uint_t)f2bf(a) | ((uint_t)f2bf(b) << 16);
}
// Load 4 consecutive bf16 (8 bytes) and widen to float4.
static __device__ __forceinline__ float4 load_bf4(const ushort_t* p) {
    uint2 u = *(const uint2*)p;
    float4 f;
    f.x = __uint_as_float(u.x << 16);
    f.y = __uint_as_float(u.x & 0xffff0000u);
    f.z = __uint_as_float(u.y << 16);
    f.w = __uint_as_float(u.y & 0xffff0000u);
    return f;
}

__global__ __launch_bounds__(64) void zero_out_k(float* out) {
    if (threadIdx.x == 0 && blockIdx.x == 0) out[0] = 0.0f;
}

__global__ __launch_bounds__(256) void zero_ints_k(int* p, int n) {
    int i = blockIdx.x * 256 + threadIdx.x;
    if (i < n) p[i] = 0;
}

__global__ __launch_bounds__(256) void count_deg_k(int* cnt, const int* __restrict__ dst, int e) {
    int i = blockIdx.x * 256 + threadIdx.x;
    if (i < e) atomicAdd(&cnt[dst[i]], 1);
}

__global__ __launch_bounds__(256) void dis_k(const int* __restrict__ cnt, float* dis, int n) {
    int i = blockIdx.x * 256 + threadIdx.x;
    if (i < n) dis[i] = rsqrtf((float)cnt[i] + 1.0f);
}

// Transpose + convert: Wt[n*K + k] = bf16(W[k*N + n]). Tiny (<=64K elems).
__global__ __launch_bounds__(256) void wt_k(const float* __restrict__ W,
                                            ushort_t* __restrict__ Wt, int K, int N) {
    int i = blockIdx.x * 256 + threadIdx.x;
    if (i < K * N) {
        int k = i / N, n = i % N;
        Wt[n * K + k] = f2bf(W[i]);
    }
}

// ---- 3-kernel exclusive scan over cnt[n] -> row_start[n] ----
__global__ __launch_bounds__(256) void scan1_k(const int* __restrict__ cnt,
                                               int* __restrict__ block_sums, int n) {
    int base = blockIdx.x * 1024 + threadIdx.x * 4;
    int s = 0;
    #pragma unroll
    for (int j = 0; j < 4; ++j) { int i = base + j; if (i < n) s += cnt[i]; }
    #pragma unroll
    for (int off = 32; off > 0; off >>= 1) s += __shfl_down(s, off);
    __shared__ int wsum[4];
    int lane = threadIdx.x & 63, wid = threadIdx.x >> 6;
    if (lane == 0) wsum[wid] = s;
    __syncthreads();
    if (threadIdx.x == 0) block_sums[blockIdx.x] = wsum[0] + wsum[1] + wsum[2] + wsum[3];
}

__global__ __launch_bounds__(64) void scan2_k(const int* __restrict__ block_sums,
                                              int* __restrict__ block_offs, int nb) {
    int t = threadIdx.x;
    int v = (t < nb) ? block_sums[t] : 0;
    int x = v;
    #pragma unroll
    for (int off = 1; off < 64; off <<= 1) {
        int tt = __shfl_up(x, off);
        if (t >= off) x += tt;
    }
    if (t < nb) block_offs[t] = x - v;
}

__global__ __launch_bounds__(256) void scan3_k(const int* __restrict__ cnt,
                                               const int* __restrict__ block_offs,
                                               int* __restrict__ row_start, int n) {
    int base = blockIdx.x * 1024 + threadIdx.x * 4;
    int e[4];
    int s = 0;
    #pragma unroll
    for (int j = 0; j < 4; ++j) {
        int i = base + j;
        e[j] = (i < n) ? cnt[i] : 0;
        s += e[j];
    }
    int lane = threadIdx.x & 63, wid = threadIdx.x >> 6;
    int x = s;
    #pragma unroll
    for (int off = 1; off < 64; off <<= 1) {
        int t = __shfl_up(x, off);
        if (lane >= off) x += t;
    }
    __shared__ int wsum[4];
    if (lane == 63) wsum[wid] = x;
    __syncthreads();
    int wave_excl = 0;
    #pragma unroll
    for (int w = 0; w < 4; ++w) if (w < wid) wave_excl += wsum[w];
    int p = block_offs[blockIdx.x] + wave_excl + (x - s);
    #pragma unroll
    for (int j = 0; j < 4; ++j) {
        int i = base + j;
        if (i < n) row_start[i] = p;
        p += e[j];
    }
}

__global__ __launch_bounds__(256) void fill_csr_k(
    const int* __restrict__ src, const int* __restrict__ dst, int E,
    const int* __restrict__ row_start, int* __restrict__ fill, int* __restrict__ csr) {
    int e = blockIdx.x * 256 + threadIdx.x;
    if (e < E) {
        int d = dst[e];
        int p = atomicAdd(&fill[d], 1);
        csr[row_start[d] + p] = src[e];
    }
}

// ---------------------------------------------------------------------------
// MFMA GEMM: Hb[m][n] = bf16( (sum_k A[m][k] * Wt[n][k]) * dis[m] )
// A: fp32 (AFP32, converted in staging) or bf16. Wt: [N,K] bf16.
// Block = WM*WN waves; each wave computes 64x64 via 4x4 grid of 16x16x32.
// LDS: As/Bs rows padded to 40 ushorts (80 B) -> conflict-free b128 frag reads.
// Epilogue round-trips C through LDS for coalesced 16-B bf16 stores.
// ---------------------------------------------------------------------------
template<int WM, int WN, bool AFP32>
__global__ __launch_bounds__(WM * WN * 64) void gemm_mfma_k(
    const void* __restrict__ Av, const ushort_t* __restrict__ Wt,
    const float* __restrict__ dis, ushort_t* __restrict__ Hb,
    int M, int K, int N)
{
    constexpr int BM = WM * 64, BN = WN * 64, NT = WM * WN * 64;
    constexpr int LDA = 40;  // 32 + 8 pad (ushorts)
    constexpr int STG = (BM + BN) * LDA * 2;
    constexpr int CSZ = BM * BN * 2;
    constexpr int SMEM = STG > CSZ ? STG : CSZ;
    __shared__ __align__(16) char smem[SMEM];
    ushort_t* As = (ushort_t*)smem;
    ushort_t* Bs = As + BM * LDA;
    ushort_t* Cs = (ushort_t*)smem;

    const int tid  = threadIdx.x;
    const int lane = tid & 63;
    const int wave = tid >> 6;
    const int quad = lane >> 4, l16 = lane & 15;
    const int wm = wave / WN, wn = wave % WN;
    const int tile_m = blockIdx.y * BM, tile_n = blockIdx.x * BN;

    v4f acc[4][4];
    #pragma unroll
    for (int i = 0; i < 4; ++i)
        #pragma unroll
        for (int j = 0; j < 4; ++j)
            acc[i][j] = (v4f){0.f, 0.f, 0.f, 0.f};

    for (int k0 = 0; k0 < K; k0 += 32) {
        // stage A tile [BM][32]
        for (int c = tid; c < BM * 4; c += NT) {
            int r = c >> 2, kc = (c & 3) * 8;
            int gr = tile_m + r;
            uint4 w = make_uint4(0, 0, 0, 0);
            if (gr < M) {
                if constexpr (AFP32) {
                    const float* p = (const float*)Av + (long)gr * K + k0 + kc;
                    float4 f0 = *(const float4*)p;
                    float4 f1 = *(const float4*)(p + 4);
                    w.x = pack2(f0.x, f0.y); w.y = pack2(f0.z, f0.w);
                    w.z = pack2(f1.x, f1.y); w.w = pack2(f1.z, f1.w);
                } else {
                    w = *(const uint4*)((const ushort_t*)Av + (long)gr * K + k0 + kc);
                }
            }
            *(uint4*)&As[r * LDA + kc] = w;
        }
        // stage B tile [BN][32] from Wt (n-major, k-contiguous: same as A)
        for (int c = tid; c < BN * 4; c += NT) {
            int r = c >> 2, kc = (c & 3) * 8;
            uint4 w = *(const uint4*)(Wt + (long)(tile_n + r) * K + k0 + kc);
            *(uint4*)&Bs[r * LDA + kc] = w;
        }
        __syncthreads();

        v8s a[4], b[4];
        #pragma unroll
        for (int f = 0; f < 4; ++f)
            a[f] = *(const v8s*)&As[(wm * 64 + f * 16 + l16) * LDA + quad * 8];
        #pragma unroll
        for (int f = 0; f < 4; ++f)
            b[f] = *(const v8s*)&Bs[(wn * 64 + f * 16 + l16) * LDA + quad * 8];
        #pragma unroll
        for (int i = 0; i < 4; ++i)
            #pragma unroll
            for (int j = 0; j < 4; ++j)
                acc[i][j] = __builtin_amdgcn_mfma_f32_16x16x32_bf16(a[i], b[j], acc[i][j], 0, 0, 0);
        __syncthreads();
    }

    // epilogue: C/D layout col=lane&15, row=quad*4+reg
    #pragma unroll
    for (int i = 0; i < 4; ++i) {
        int rl0 = wm * 64 + i * 16 + quad * 4;
        #pragma unroll
        for (int r = 0; r < 4; ++r) {
            int gr = tile_m + rl0 + r;
            float s = (gr < M) ? dis[gr] : 0.f;
            #pragma unroll
            for (int j = 0; j < 4; ++j)
                Cs[(rl0 + r) * BN + wn * 64 + j * 16 + l16] = f2bf(acc[i][j][r] * s);
        }
    }
    __syncthreads();
    constexpr int CCH = BN / 8;
    for (int c = tid; c < BM * CCH; c += NT) {
        int r = c / CCH, col = (c % CCH) * 8;
        int gr = tile_m + r;
        if (gr < M)
            *(uint4*)(Hb + (long)gr * N + tile_n + col) = *(const uint4*)&Cs[r * BN + col];
    }
}

// OUT[i] = bf16(relu(dis[i] * (H[i] + sum_{s in nbrs(i)} H[s]) + b)), H bf16.
template<int F>
__global__ __launch_bounds__(256) void gather_relu_k(
    const ushort_t* __restrict__ Hb, ushort_t* __restrict__ OUT,
    const int* __restrict__ row_start, const int* __restrict__ cnt,
    const int* __restrict__ csr, const float* __restrict__ dis,
    const float* __restrict__ bias, int n)
{
    constexpr int L = F / 4;
    constexpr int NPB = 256 / L;
    int node = blockIdx.x * NPB + threadIdx.x / L;
    if (node >= n) return;
    int c = (threadIdx.x % L) * 4;

    float4 acc = load_bf4(Hb + (long)node * F + c);   // self-loop
    int base = row_start[node];
    int deg  = cnt[node];
    if constexpr (L == 64) {  // wave-uniform
        base = __builtin_amdgcn_readfirstlane(base);
        deg  = __builtin_amdgcn_readfirstlane(deg);
    }
    int k = 0;
    for (; k + 3 < deg; k += 4) {
        int s0 = csr[base + k];
        int s1 = csr[base + k + 1];
        int s2 = csr[base + k + 2];
        int s3 = csr[base + k + 3];
        float4 v0 = load_bf4(Hb + (long)s0 * F + c);
        float4 v1 = load_bf4(Hb + (long)s1 * F + c);
        float4 v2 = load_bf4(Hb + (long)s2 * F + c);
        float4 v3 = load_bf4(Hb + (long)s3 * F + c);
        acc.x += (v0.x + v1.x) + (v2.x + v3.x);
        acc.y += (v0.y + v1.y) + (v2.y + v3.y);
        acc.z += (v0.z + v1.z) + (v2.z + v3.z);
        acc.w += (v0.w + v1.w) + (v2.w + v3.w);
    }
    for (; k < deg; ++k) {
        int s0 = csr[base + k];
        float4 v0 = load_bf4(Hb + (long)s0 * F + c);
        acc.x += v0.x; acc.y += v0.y; acc.z += v0.z; acc.w += v0.w;
    }
    float di = dis[node];
    float4 bb = *(const float4*)(bias + c);
    ushort4 o;
    o.x = f2bf(fmaxf(fmaf(di, acc.x, bb.x), 0.f));
    o.y = f2bf(fmaxf(fmaf(di, acc.y, bb.y), 0.f));
    o.z = f2bf(fmaxf(fmaf(di, acc.z, bb.z), 0.f));
    o.w = f2bf(fmaxf(fmaf(di, acc.w, bb.w), 0.f));
    *(ushort4*)(OUT + (long)node * F + c) = o;
}

// Layer-3: reduce sum(relu)/64 into out.
__global__ __launch_bounds__(256) void gather_relu_reduce_k(
    const ushort_t* __restrict__ Hb,
    const int* __restrict__ row_start, const int* __restrict__ cnt,
    const int* __restrict__ csr, const float* __restrict__ dis,
    const float* __restrict__ bias, int n, float* __restrict__ out)
{
    constexpr int F = 64, L = 16, NPB = 16;
    int node = blockIdx.x * NPB + threadIdx.x / L;
    int c = (threadIdx.x % L) * 4;
    float val = 0.f;
    if (node < n) {
        float4 acc = load_bf4(Hb + (long)node * F + c);
        int base = row_start[node];
        int deg  = cnt[node];
        int k = 0;
        for (; k + 3 < deg; k += 4) {
            int s0 = csr[base + k];
            int s1 = csr[base + k + 1];
            int s2 = csr[base + k + 2];
            int s3 = csr[base + k + 3];
            float4 v0 = load_bf4(Hb + (long)s0 * F + c);
            float4 v1 = load_bf4(Hb + (long)s1 * F + c);
            float4 v2 = load_bf4(Hb + (long)s2 * F + c);
            float4 v3 = load_bf4(Hb + (long)s3 * F + c);
            acc.x += (v0.x + v1.x) + (v2.x + v3.x);
            acc.y += (v0.y + v1.y) + (v2.y + v3.y);
            acc.z += (v0.z + v1.z) + (v2.z + v3.z);
            acc.w += (v0.w + v1.w) + (v2.w + v3.w);
        }
        for (; k < deg; ++k) {
            int s0 = csr[base + k];
            float4 v0 = load_bf4(Hb + (long)s0 * F + c);
            acc.x += v0.x; acc.y += v0.y; acc.z += v0.z; acc.w += v0.w;
        }
        float di = dis[node];
        float4 bb = *(const float4*)(bias + c);
        val = fmaxf(fmaf(di, acc.x, bb.x), 0.f)
            + fmaxf(fmaf(di, acc.y, bb.y), 0.f)
            + fmaxf(fmaf(di, acc.z, bb.z), 0.f)
            + fmaxf(fmaf(di, acc.w, bb.w), 0.f);
    }
    #pragma unroll
    for (int off = 32; off > 0; off >>= 1) val += __shfl_down(val, off);
    __shared__ float wsum[4];
    int lane = threadIdx.x & 63, wid = threadIdx.x >> 6;
    if (lane == 0) wsum[wid] = val;
    __syncthreads();
    if (threadIdx.x == 0) {
        float s = (wsum[0] + wsum[1] + wsum[2] + wsum[3]) * (1.0f / 64.0f);
        atomicAdd(out, s);
    }
}

extern "C" void kernel_launch(void* const* d_in, const int* in_sizes, int n_in,
                              void* d_out, int out_size, void* d_ws, size_t ws_size,
                              hipStream_t stream) {
    const float* X[3]  = {(const float*)d_in[0], (const float*)d_in[1], (const float*)d_in[2]};
    const int*   EI[3] = {(const int*)d_in[3], (const int*)d_in[4], (const int*)d_in[5]};
    const float* W1 = (const float*)d_in[6];
    const float* b1 = (const float*)d_in[7];
    const float* W2 = (const float*)d_in[8];
    const float* b2 = (const float*)d_in[9];
    const float* W3 = (const float*)d_in[10];
    const float* b3 = (const float*)d_in[11];
    float* out = (float*)d_out;

    const int Nn = in_sizes[0] / 256;   // 50000
    const int E  = in_sizes[3] / 2;     // 800000

    // Workspace layout (bytes, all 16-aligned):
    // Ab: bf16[Nn*256] | Hb: bf16[Nn*256] | Wt1[256*256] | Wt2[128*256] | Wt3[64*128]
    // dis: f32[Nn] | cnt[Nn] | fill[Nn] | row_start[Nn+1] | csr[E] | bs[64] | bo[64]
    ushort_t* Ab  = (ushort_t*)d_ws;
    ushort_t* Hb  = Ab + (size_t)Nn * 256;
    ushort_t* Wt1 = Hb + (size_t)Nn * 256;
    ushort_t* Wt2 = Wt1 + 256 * 256;
    ushort_t* Wt3 = Wt2 + 128 * 256;
    float* dis = (float*)(Wt3 + 64 * 128);
    int* cnt        = (int*)(dis + Nn);
    int* fill       = cnt + Nn;
    int* row_start  = fill + Nn;
    int* csr        = row_start + Nn + 1;
    int* block_sums = csr + E;
    int* block_offs = block_sums + 64;

    zero_out_k<<<1, 64, 0, stream>>>(out);
    wt_k<<<(256 * 256 + 255) / 256, 256, 0, stream>>>(W1, Wt1, 256, 256);
    wt_k<<<(256 * 128 + 255) / 256, 256, 0, stream>>>(W2, Wt2, 256, 128);
    wt_k<<<(128 * 64 + 255) / 256, 256, 0, stream>>>(W3, Wt3, 128, 64);

    const int nb_n = (Nn + 255) / 256;
    const int nb_e = (E + 255) / 256;
    const int nb_s = (Nn + 1023) / 1024;

    for (int g = 0; g < 3; ++g) {
        const int* src = EI[g];
        const int* dst = EI[g] + E;

        // --- CSR build (shared by all 3 layers of this graph) ---
        zero_ints_k<<<(2 * Nn + 255) / 256, 256, 0, stream>>>(cnt, 2 * Nn); // cnt+fill
        count_deg_k<<<nb_e, 256, 0, stream>>>(cnt, dst, E);
        dis_k<<<nb_n, 256, 0, stream>>>(cnt, dis, Nn);
        scan1_k<<<nb_s, 256, 0, stream>>>(cnt, block_sums, Nn);
        scan2_k<<<1, 64, 0, stream>>>(block_sums, block_offs, nb_s);
        scan3_k<<<nb_s, 256, 0, stream>>>(cnt, block_offs, row_start, Nn);
        fill_csr_k<<<nb_e, 256, 0, stream>>>(src, dst, E, row_start, fill, csr);

        // ---- Layer 1: X fp32 [Nn,256] @ Wt1 -> Hb [Nn,256] ----
        {
            dim3 grid(256 / 256, (Nn + 63) / 64);     // BM=64, BN=256
            gemm_mfma_k<1, 4, true><<<grid, 256, 0, stream>>>(X[g], Wt1, dis, Hb, Nn, 256, 256);
            gather_relu_k<256><<<(Nn + 3) / 4, 256, 0, stream>>>(
                Hb, Ab, row_start, cnt, csr, dis, b1, Nn);
        }
        // ---- Layer 2: Ab bf16 [Nn,256] @ Wt2 -> Hb [Nn,128] ----
        {
            dim3 grid(128 / 128, (Nn + 127) / 128);   // BM=128, BN=128
            gemm_mfma_k<2, 2, false><<<grid, 256, 0, stream>>>(Ab, Wt2, dis, Hb, Nn, 256, 128);
            gather_relu_k<128><<<(Nn + 7) / 8, 256, 0, stream>>>(
                Hb, Ab, row_start, cnt, csr, dis, b2, Nn);
        }
        // ---- Layer 3: Ab bf16 [Nn,128] @ Wt3 -> Hb [Nn,64], fused reduce ----
        {
            dim3 grid(64 / 64, (Nn + 127) / 128);     // BM=128, BN=64
            gemm_mfma_k<2, 1, false><<<grid, 128, 0, stream>>>(Ab, Wt3, dis, Hb, Nn, 128, 64);
            gather_relu_reduce_k<<<(Nn + 15) / 16, 256, 0, stream>>>(
                Hb, row_start, cnt, csr, dis, b3, Nn, out);
        }
    }
}

// Round 5
// 836.256 us; speedup vs baseline: 18.4453x; 1.2818x over previous
//
#include <hip/hip_runtime.h>
#include <hip/hip_bf16.h>

// ---------------------------------------------------------------------------
// GCN stack: 3 graphs x 3 layers (256->256->128->64), final scalar = sum/64.
// Math: with h' = (x@W) * dis[row],
//   out[i] = relu( dis[i] * (h'[i] + sum_{e: dst=i} h'[src[e]]) + b )
// R5: (a) batch all 3 graphs into one pipeline (one CSR chain, one launch per
// layer stage) when ws_size permits, per-graph fallback otherwise;
// (b) layer-1 H stored as fp8 e4m3 (halves the dominant gather's bytes).
// ---------------------------------------------------------------------------

typedef unsigned short ushort_t;
typedef unsigned int uint_t;
typedef unsigned char uchar_t;
typedef __attribute__((ext_vector_type(8))) short v8s;   // 8 bf16
typedef __attribute__((ext_vector_type(4))) float v4f;   // MFMA accum
typedef __attribute__((ext_vector_type(2))) float v2f;

struct FP3 { const float* a; const float* b; const float* c; };
struct IP3 { const int* a; const int* b; const int* c; };

static __device__ __forceinline__ ushort_t f2bf(float f) {
    uint_t u = __float_as_uint(f);
    u += 0x7fffu + ((u >> 16) & 1u);   // RNE
    return (ushort_t)(u >> 16);
}
static __device__ __forceinline__ uint_t pack2(float a, float b) {
    return (uint_t)f2bf(a) | ((uint_t)f2bf(b) << 16);
}
static __device__ __forceinline__ float4 load_bf4(const ushort_t* p) {
    uint2 u = *(const uint2*)p;
    float4 f;
    f.x = __uint_as_float(u.x << 16);
    f.y = __uint_as_float(u.x & 0xffff0000u);
    f.z = __uint_as_float(u.y << 16);
    f.w = __uint_as_float(u.y & 0xffff0000u);
    return f;
}

// fp8 e4m3fn encode, RNE, clamp to +-448.
static __device__ __forceinline__ uint_t f2fp8(float f) {
    uint_t u = __float_as_uint(f);
    uint_t s = (u >> 24) & 0x80u;
    uint_t a = u & 0x7fffffffu;
    uint_t r;
    if (a >= 0x43E00000u) {            // |f| >= 448
        r = 0x7Eu;
    } else if (a < 0x3C800000u) {      // |f| < 2^-6: fp8 subnormal, unit 2^-9
        r = (uint_t)(int)rintf(__uint_as_float(a) * 512.0f);
    } else {
        uint_t t = a + 0x7FFFFu + ((a >> 20) & 1u);
        r = (t >> 20) - 960u;
        if (r > 0x7Eu) r = 0x7Eu;
    }
    return s | r;
}
static __device__ __forceinline__ float fp8f(uint_t b) {
    uint_t t = (b & 0x7Fu) << 20;
    float f = __uint_as_float(t) * 0x1.0p+120f;
    return __uint_as_float(__float_as_uint(f) | ((b & 0x80u) << 24));
}
static __device__ __forceinline__ float4 load_fp84(const uchar_t* p) {
    uint_t w = *(const uint_t*)p;
    float4 f;
#if __has_builtin(__builtin_amdgcn_cvt_pk_f32_fp8)
    v2f lo = __builtin_amdgcn_cvt_pk_f32_fp8((int)w, false);
    v2f hi = __builtin_amdgcn_cvt_pk_f32_fp8((int)w, true);
    f.x = lo[0]; f.y = lo[1]; f.z = hi[0]; f.w = hi[1];
#else
    f.x = fp8f(w & 0xffu); f.y = fp8f((w >> 8) & 0xffu);
    f.z = fp8f((w >> 16) & 0xffu); f.w = fp8f(w >> 24);
#endif
    return f;
}

// ---------------------------------------------------------------------------
__global__ __launch_bounds__(256) void zero2_k(int* a, int* b, float* out, int n) {
    int i = blockIdx.x * 256 + threadIdx.x;
    if (i < n) { a[i] = 0; b[i] = 0; }
    if (i == 0) out[0] = 0.0f;
}

// All 3 weight transposes+converts in one launch.
__global__ __launch_bounds__(256) void wt_all_k(
    const float* __restrict__ W1, const float* __restrict__ W2, const float* __restrict__ W3,
    ushort_t* __restrict__ Wt1, ushort_t* __restrict__ Wt2, ushort_t* __restrict__ Wt3) {
    int i = blockIdx.x * 256 + threadIdx.x;
    if (i < 65536) {
        int k = i >> 8, n = i & 255;
        Wt1[n * 256 + k] = f2bf(W1[i]);
    } else if (i < 98304) {
        int j = i - 65536; int k = j >> 7, n = j & 127;
        Wt2[n * 256 + k] = f2bf(W2[j]);
    } else if (i < 106496) {
        int j = i - 98304; int k = j >> 6, n = j & 63;
        Wt3[n * 128 + k] = f2bf(W3[j]);
    }
}

__global__ __launch_bounds__(256) void count_b_k(IP3 ei, int E, int Nn, int* cnt) {
    int g = blockIdx.y;
    const int* eb = g == 0 ? ei.a : (g == 1 ? ei.b : ei.c);
    int e = blockIdx.x * 256 + threadIdx.x;
    if (e < E) atomicAdd(&cnt[g * Nn + eb[E + e]], 1);
}

__global__ __launch_bounds__(256) void dis_b_k(const int* __restrict__ cnt, float* dis, int n) {
    int i = blockIdx.x * 256 + threadIdx.x;
    if (i < n) dis[i] = rsqrtf((float)cnt[i] + 1.0f);
}

// ---- 3-kernel exclusive scan over cnt[n] (chunk = 4096, <=64 chunks) ----
__global__ __launch_bounds__(256) void scan1_k(const int* __restrict__ cnt,
                                               int* __restrict__ bsums, int n) {
    int base = blockIdx.x * 4096 + threadIdx.x * 16;
    int s = 0;
    #pragma unroll
    for (int j = 0; j < 16; ++j) { int i = base + j; if (i < n) s += cnt[i]; }
    #pragma unroll
    for (int off = 32; off > 0; off >>= 1) s += __shfl_down(s, off);
    __shared__ int wsum[4];
    int lane = threadIdx.x & 63, wid = threadIdx.x >> 6;
    if (lane == 0) wsum[wid] = s;
    __syncthreads();
    if (threadIdx.x == 0) bsums[blockIdx.x] = wsum[0] + wsum[1] + wsum[2] + wsum[3];
}

__global__ __launch_bounds__(64) void scan2_k(const int* __restrict__ bsums,
                                              int* __restrict__ boffs, int nb) {
    int t = threadIdx.x;
    int v = (t < nb) ? bsums[t] : 0;
    int x = v;
    #pragma unroll
    for (int off = 1; off < 64; off <<= 1) {
        int tt = __shfl_up(x, off);
        if (t >= off) x += tt;
    }
    if (t < nb) boffs[t] = x - v;
}

__global__ __launch_bounds__(256) void scan3_k(const int* __restrict__ cnt,
                                               const int* __restrict__ boffs,
                                               int* __restrict__ rs, int n) {
    int base = blockIdx.x * 4096 + threadIdx.x * 16;
    int e[16];
    int s = 0;
    #pragma unroll
    for (int j = 0; j < 16; ++j) {
        int i = base + j;
        e[j] = (i < n) ? cnt[i] : 0;
        s += e[j];
    }
    int lane = threadIdx.x & 63, wid = threadIdx.x >> 6;
    int x = s;
    #pragma unroll
    for (int off = 1; off < 64; off <<= 1) {
        int t = __shfl_up(x, off);
        if (lane >= off) x += t;
    }
    __shared__ int wsum[4];
    if (lane == 63) wsum[wid] = x;
    __syncthreads();
    int we = 0;
    #pragma unroll
    for (int w = 0; w < 4; ++w) if (w < wid) we += wsum[w];
    int p = boffs[blockIdx.x] + we + (x - s);
    #pragma unroll
    for (int j = 0; j < 16; ++j) {
        int i = base + j;
        if (i < n) rs[i] = p;
        p += e[j];
    }
}

// csr holds LOCAL src ids; rs values are absolute offsets into the 3E csr.
__global__ __launch_bounds__(256) void fill_b_k(IP3 ei, int E, int Nn,
    const int* __restrict__ rs, int* __restrict__ fill, int* __restrict__ csr) {
    int g = blockIdx.y;
    const int* eb = g == 0 ? ei.a : (g == 1 ? ei.b : ei.c);
    int e = blockIdx.x * 256 + threadIdx.x;
    if (e < E) {
        int d = eb[E + e];
        int gd = g * Nn + d;
        int p = atomicAdd(&fill[gd], 1);
        csr[rs[gd] + p] = eb[e];
    }
}

// ---------------------------------------------------------------------------
// MFMA GEMM over M = Bc*Nn batched rows: out[m][n] = cvt((sum_k A*Wt)*dis[m])
// AFP32: A rows come from per-graph X pointers (fp32->bf16 in staging).
// OUT8: epilogue stores fp8 e4m3 instead of bf16.
// ---------------------------------------------------------------------------
template<int WM, int WN, bool AFP32, bool OUT8>
__global__ __launch_bounds__(WM * WN * 64) void gemm_mfma_k(
    FP3 xp, const ushort_t* __restrict__ Ab,
    const ushort_t* __restrict__ Wt, const float* __restrict__ dis,
    void* __restrict__ outv, int M, int K, int N, int Nn)
{
    constexpr int BM = WM * 64, BN = WN * 64, NT = WM * WN * 64;
    constexpr int LDA = 40;  // ushorts, pad breaks bank conflicts
    constexpr int STG = (BM + BN) * LDA * 2;
    constexpr int CSZ = BM * BN * (OUT8 ? 1 : 2);
    constexpr int SMEM = STG > CSZ ? STG : CSZ;
    __shared__ __align__(16) char smem[SMEM];
    ushort_t* As = (ushort_t*)smem;
    ushort_t* Bs = As + BM * LDA;

    const int tid  = threadIdx.x;
    const int lane = tid & 63;
    const int wave = tid >> 6;
    const int quad = lane >> 4, l16 = lane & 15;
    const int wm = wave / WN, wn = wave % WN;
    const int tile_m = blockIdx.y * BM, tile_n = blockIdx.x * BN;

    v4f acc[4][4];
    #pragma unroll
    for (int i = 0; i < 4; ++i)
        #pragma unroll
        for (int j = 0; j < 4; ++j)
            acc[i][j] = (v4f){0.f, 0.f, 0.f, 0.f};

    const float* Xrow = nullptr;
    int ar = 0, akc = 0;
    if constexpr (AFP32) {
        static_assert(BM * 4 == NT, "AFP32 staging assumes one chunk/thread");
        ar = tid >> 2; akc = (tid & 3) * 8;
        int gr = tile_m + ar;
        if (gr < M) {
            int lg = gr / Nn;
            int rl = gr - lg * Nn;
            const float* Xg = lg == 0 ? xp.a : (lg == 1 ? xp.b : xp.c);
            Xrow = Xg + (long)rl * K;
        }
    }

    for (int k0 = 0; k0 < K; k0 += 32) {
        if constexpr (AFP32) {
            uint4 w = make_uint4(0, 0, 0, 0);
            if (Xrow) {
                float4 f0 = *(const float4*)(Xrow + k0 + akc);
                float4 f1 = *(const float4*)(Xrow + k0 + akc + 4);
                w.x = pack2(f0.x, f0.y); w.y = pack2(f0.z, f0.w);
                w.z = pack2(f1.x, f1.y); w.w = pack2(f1.z, f1.w);
            }
            *(uint4*)&As[ar * LDA + akc] = w;
        } else {
            for (int cch = tid; cch < BM * 4; cch += NT) {
                int r = cch >> 2, kc = (cch & 3) * 8;
                int gr = tile_m + r;
                uint4 w = make_uint4(0, 0, 0, 0);
                if (gr < M) w = *(const uint4*)(Ab + (long)gr * K + k0 + kc);
                *(uint4*)&As[r * LDA + kc] = w;
            }
        }
        for (int cch = tid; cch < BN * 4; cch += NT) {
            int r = cch >> 2, kc = (cch & 3) * 8;
            uint4 w = *(const uint4*)(Wt + (long)(tile_n + r) * K + k0 + kc);
            *(uint4*)&Bs[r * LDA + kc] = w;
        }
        __syncthreads();

        v8s a[4], b[4];
        #pragma unroll
        for (int f = 0; f < 4; ++f)
            a[f] = *(const v8s*)&As[(wm * 64 + f * 16 + l16) * LDA + quad * 8];
        #pragma unroll
        for (int f = 0; f < 4; ++f)
            b[f] = *(const v8s*)&Bs[(wn * 64 + f * 16 + l16) * LDA + quad * 8];
        #pragma unroll
        for (int i = 0; i < 4; ++i)
            #pragma unroll
            for (int j = 0; j < 4; ++j)
                acc[i][j] = __builtin_amdgcn_mfma_f32_16x16x32_bf16(a[i], b[j], acc[i][j], 0, 0, 0);
        __syncthreads();
    }

    // epilogue: C/D layout col=lane&15, row=quad*4+reg; LDS round-trip.
    if constexpr (OUT8) {
        uchar_t* Cs = (uchar_t*)smem;
        #pragma unroll
        for (int i = 0; i < 4; ++i) {
            int rl0 = wm * 64 + i * 16 + quad * 4;
            #pragma unroll
            for (int r = 0; r < 4; ++r) {
                int gr = tile_m + rl0 + r;
                float s = (gr < M) ? dis[gr] : 0.f;
                #pragma unroll
                for (int j = 0; j < 4; ++j)
                    Cs[(rl0 + r) * BN + wn * 64 + j * 16 + l16] = (uchar_t)f2fp8(acc[i][j][r] * s);
            }
        }
        __syncthreads();
        uchar_t* out8 = (uchar_t*)outv;
        constexpr int CCH = BN / 8;
        for (int cch = tid; cch < BM * CCH; cch += NT) {
            int r = cch / CCH, col = (cch % CCH) * 8;
            int gr = tile_m + r;
            if (gr < M)
                *(uint2*)(out8 + (long)gr * N + col) = *(const uint2*)&Cs[r * BN + col];
        }
    } else {
        ushort_t* Cs = (ushort_t*)smem;
        #pragma unroll
        for (int i = 0; i < 4; ++i) {
            int rl0 = wm * 64 + i * 16 + quad * 4;
            #pragma unroll
            for (int r = 0; r < 4; ++r) {
                int gr = tile_m + rl0 + r;
                float s = (gr < M) ? dis[gr] : 0.f;
                #pragma unroll
                for (int j = 0; j < 4; ++j)
                    Cs[(rl0 + r) * BN + wn * 64 + j * 16 + l16] = f2bf(acc[i][j][r] * s);
            }
        }
        __syncthreads();
        ushort_t* outb = (ushort_t*)outv;
        constexpr int CCH = BN / 8;
        for (int cch = tid; cch < BM * CCH; cch += NT) {
            int r = cch / CCH, col = (cch % CCH) * 8;
            int gr = tile_m + r;
            if (gr < M)
                *(uint4*)(outb + (long)gr * N + col) = *(const uint4*)&Cs[r * BN + col];
        }
    }
}

template<bool IN8>
static __device__ __forceinline__ float4 ldrow(const void* H, long off) {
    if constexpr (IN8) return load_fp84((const uchar_t*)H + off);
    else return load_bf4((const ushort_t*)H + off);
}

// OUT[i] = bf16(relu(dis[i]*(H[i] + sum_nbrs H[s]) + b)); H fp8 or bf16.
template<int F, bool IN8>
__global__ __launch_bounds__(256) void gather_relu_k(
    const void* __restrict__ Hv, ushort_t* __restrict__ OUT,
    const int* __restrict__ rs, const int* __restrict__ cnt,
    const int* __restrict__ csr, const float* __restrict__ dis,
    const float* __restrict__ bias, int n, int Nn)
{
    constexpr int L = F / 4;
    constexpr int NPB = 256 / L;
    int node = blockIdx.x * NPB + threadIdx.x / L;
    if (node >= n) return;
    int c = (threadIdx.x % L) * 4;
    int base = rs[node];
    int deg  = cnt[node];
    int lg   = node / Nn;
    if constexpr (L == 64) {  // node wave-uniform: scalarize
        base = __builtin_amdgcn_readfirstlane(base);
        deg  = __builtin_amdgcn_readfirstlane(deg);
        lg   = __builtin_amdgcn_readfirstlane(lg);
    }
    long gbase = (long)lg * Nn;

    float4 acc = ldrow<IN8>(Hv, (long)node * F + c);   // self-loop
    int k = 0;
    for (; k + 3 < deg; k += 4) {
        int s0 = csr[base + k];
        int s1 = csr[base + k + 1];
        int s2 = csr[base + k + 2];
        int s3 = csr[base + k + 3];
        float4 v0 = ldrow<IN8>(Hv, (gbase + s0) * F + c);
        float4 v1 = ldrow<IN8>(Hv, (gbase + s1) * F + c);
        float4 v2 = ldrow<IN8>(Hv, (gbase + s2) * F + c);
        float4 v3 = ldrow<IN8>(Hv, (gbase + s3) * F + c);
        acc.x += (v0.x + v1.x) + (v2.x + v3.x);
        acc.y += (v0.y + v1.y) + (v2.y + v3.y);
        acc.z += (v0.z + v1.z) + (v2.z + v3.z);
        acc.w += (v0.w + v1.w) + (v2.w + v3.w);
    }
    for (; k < deg; ++k) {
        int s0 = csr[base + k];
        float4 v0 = ldrow<IN8>(Hv, (gbase + s0) * F + c);
        acc.x += v0.x; acc.y += v0.y; acc.z += v0.z; acc.w += v0.w;
    }
    float di = dis[node];
    float4 bb = *(const float4*)(bias + c);
    ushort4 o;
    o.x = f2bf(fmaxf(fmaf(di, acc.x, bb.x), 0.f));
    o.y = f2bf(fmaxf(fmaf(di, acc.y, bb.y), 0.f));
    o.z = f2bf(fmaxf(fmaf(di, acc.z, bb.z), 0.f));
    o.w = f2bf(fmaxf(fmaf(di, acc.w, bb.w), 0.f));
    *(ushort4*)(OUT + (long)node * F + c) = o;
}

// Layer-3: gather + relu + global sum/64 (H bf16, F=64).
__global__ __launch_bounds__(256) void gather_reduce_k(
    const void* __restrict__ Hv,
    const int* __restrict__ rs, const int* __restrict__ cnt,
    const int* __restrict__ csr, const float* __restrict__ dis,
    const float* __restrict__ bias, int n, int Nn, float* __restrict__ out)
{
    constexpr int F = 64, L = 16, NPB = 16;
    int node = blockIdx.x * NPB + threadIdx.x / L;
    int c = (threadIdx.x % L) * 4;
    float val = 0.f;
    if (node < n) {
        const ushort_t* Hb = (const ushort_t*)Hv;
        int lg = node / Nn;
        long gbase = (long)lg * Nn;
        float4 acc = load_bf4(Hb + (long)node * F + c);
        int base = rs[node], deg = cnt[node];
        int k = 0;
        for (; k + 3 < deg; k += 4) {
            int s0 = csr[base + k];
            int s1 = csr[base + k + 1];
            int s2 = csr[base + k + 2];
            int s3 = csr[base + k + 3];
            float4 v0 = load_bf4(Hb + (gbase + s0) * F + c);
            float4 v1 = load_bf4(Hb + (gbase + s1) * F + c);
            float4 v2 = load_bf4(Hb + (gbase + s2) * F + c);
            float4 v3 = load_bf4(Hb + (gbase + s3) * F + c);
            acc.x += (v0.x + v1.x) + (v2.x + v3.x);
            acc.y += (v0.y + v1.y) + (v2.y + v3.y);
            acc.z += (v0.z + v1.z) + (v2.z + v3.z);
            acc.w += (v0.w + v1.w) + (v2.w + v3.w);
        }
        for (; k < deg; ++k) {
            int s0 = csr[base + k];
            float4 v0 = load_bf4(Hb + (gbase + s0) * F + c);
            acc.x += v0.x; acc.y += v0.y; acc.z += v0.z; acc.w += v0.w;
        }
        float di = dis[node];
        float4 bb = *(const float4*)(bias + c);
        val = fmaxf(fmaf(di, acc.x, bb.x), 0.f)
            + fmaxf(fmaf(di, acc.y, bb.y), 0.f)
            + fmaxf(fmaf(di, acc.z, bb.z), 0.f)
            + fmaxf(fmaf(di, acc.w, bb.w), 0.f);
    }
    #pragma unroll
    for (int off = 32; off > 0; off >>= 1) val += __shfl_down(val, off);
    __shared__ float wsum[4];
    int lane = threadIdx.x & 63, wid = threadIdx.x >> 6;
    if (lane == 0) wsum[wid] = val;
    __syncthreads();
    if (threadIdx.x == 0) {
        float s = (wsum[0] + wsum[1] + wsum[2] + wsum[3]) * (1.0f / 64.0f);
        atomicAdd(out, s);
    }
}

extern "C" void kernel_launch(void* const* d_in, const int* in_sizes, int n_in,
                              void* d_out, int out_size, void* d_ws, size_t ws_size,
                              hipStream_t stream) {
    const float* X[3]  = {(const float*)d_in[0], (const float*)d_in[1], (const float*)d_in[2]};
    const int*   EI[3] = {(const int*)d_in[3], (const int*)d_in[4], (const int*)d_in[5]};
    const float* W1 = (const float*)d_in[6];
    const float* b1 = (const float*)d_in[7];
    const float* W2 = (const float*)d_in[8];
    const float* b2 = (const float*)d_in[9];
    const float* W3 = (const float*)d_in[10];
    const float* b3 = (const float*)d_in[11];
    float* out = (float*)d_out;

    const int Nn = in_sizes[0] / 256;   // 50000
    const int E  = in_sizes[3] / 2;     // 800000
    const int B  = 3;

    // ---- workspace layout (512B-aligned regions) ----
    char* base = (char*)d_ws;
    size_t off = 0;
    auto take = [&](size_t bytes) -> void* {
        void* r = base + off;
        off += (bytes + 511) & ~(size_t)511;
        return r;
    };
    float* dis = (float*)take((size_t)B * Nn * 4);
    int* cnt   = (int*)take((size_t)B * Nn * 4);
    int* fill  = (int*)take((size_t)B * Nn * 4);
    int* rs    = (int*)take((size_t)B * Nn * 4);
    int* csr   = (int*)take((size_t)B * E * 4);
    int* bsums = (int*)take(64 * 4);
    int* boffs = (int*)take(64 * 4);
    ushort_t* Wt1 = (ushort_t*)take(256 * 256 * 2);
    ushort_t* Wt2 = (ushort_t*)take(128 * 256 * 2);
    ushort_t* Wt3 = (ushort_t*)take(64 * 128 * 2);
    size_t fixed = off;
    size_t abFull = ((size_t)B * Nn * 256 * 2 + 511) & ~(size_t)511;
    size_t hbFull = ((size_t)B * Nn * 256 + 511) & ~(size_t)511;
    const bool batched = ws_size >= fixed + abFull + hbFull;
    const int Bc = batched ? 3 : 1;
    ushort_t* Ab = (ushort_t*)take((size_t)Bc * Nn * 256 * 2);
    void* Hsh = take((size_t)Bc * Nn * 256);   // fp8[Bc*Nn,256] / bf16[Bc*Nn,128] / bf16[Bc*Nn,64]

    IP3 ei = {EI[0], EI[1], EI[2]};
    const int nb_e  = (E + 255) / 256;
    const int nAll  = B * Nn;
    const int nb_sc = (nAll + 4095) / 4096;   // 37 <= 64

    // ---- prep + batched CSR build (all 3 graphs) ----
    zero2_k<<<(nAll + 255) / 256, 256, 0, stream>>>(cnt, fill, out, nAll);
    wt_all_k<<<(106496 + 255) / 256, 256, 0, stream>>>(W1, W2, W3, Wt1, Wt2, Wt3);
    count_b_k<<<dim3(nb_e, 3), 256, 0, stream>>>(ei, E, Nn, cnt);
    dis_b_k<<<(nAll + 255) / 256, 256, 0, stream>>>(cnt, dis, nAll);
    scan1_k<<<nb_sc, 256, 0, stream>>>(cnt, bsums, nAll);
    scan2_k<<<1, 64, 0, stream>>>(bsums, boffs, nb_sc);
    scan3_k<<<nb_sc, 256, 0, stream>>>(cnt, boffs, rs, nAll);
    fill_b_k<<<dim3(nb_e, 3), 256, 0, stream>>>(ei, E, Nn, rs, fill, csr);

    // ---- layer pipeline (batched over Bc graphs per pass) ----
    for (int g0 = 0; g0 < B; g0 += Bc) {
        const int M = Bc * Nn;
        FP3 xp;
        if (Bc == 3) { xp.a = X[0]; xp.b = X[1]; xp.c = X[2]; }
        else         { xp.a = X[g0]; xp.b = X[g0]; xp.c = X[g0]; }
        const float* disl = dis + (size_t)g0 * Nn;
        const int*   rsl  = rs  + (size_t)g0 * Nn;
        const int*   cntl = cnt + (size_t)g0 * Nn;

        // L1: X fp32 [M,256] @ Wt1 -> Hsh fp8 [M,256]
        gemm_mfma_k<1, 4, true, true><<<dim3(1, (M + 63) / 64), 256, 0, stream>>>(
            xp, nullptr, Wt1, disl, Hsh, M, 256, 256, Nn);
        gather_relu_k<256, true><<<(M + 3) / 4, 256, 0, stream>>>(
            Hsh, Ab, rsl, cntl, csr, disl, b1, M, Nn);

        // L2: Ab bf16 [M,256] @ Wt2 -> Hsh bf16 [M,128]
        gemm_mfma_k<2, 2, false, false><<<dim3(1, (M + 127) / 128), 256, 0, stream>>>(
            xp, Ab, Wt2, disl, Hsh, M, 256, 128, Nn);
        gather_relu_k<128, false><<<(M + 7) / 8, 256, 0, stream>>>(
            Hsh, Ab, rsl, cntl, csr, disl, b2, M, Nn);

        // L3: Ab bf16 [M,128] @ Wt3 -> Hsh bf16 [M,64], fused scalar reduce
        gemm_mfma_k<2, 1, false, false><<<dim3(1, (M + 127) / 128), 128, 0, stream>>>(
            xp, Ab, Wt3, disl, Hsh, M, 128, 64, Nn);
        gather_reduce_k<<<(M + 15) / 16, 256, 0, stream>>>(
            Hsh, rsl, cntl, csr, disl, b3, M, Nn, out);
    }
}

// Round 6
// 733.951 us; speedup vs baseline: 21.0164x; 1.1394x over previous
//
#include <hip/hip_runtime.h>
#include <hip/hip_bf16.h>

// ---------------------------------------------------------------------------
// GCN stack: 3 graphs x 3 layers (256->256->128->64), final scalar = sum/64.
// Math: with h' = (x@W) * dis[row],
//   out[i] = relu( dis[i] * (h'[i] + sum_{e: dst=i} h'[src[e]]) + b )
// R6: all gather-side H buffers in fp8 e4m3 (L1 already was; now L2+L3);
// two-stage final reduction (block partials + one reduce kernel) replaces
// 9375 same-address atomics; csr indices stored as ushort (ids < 65536).
// ---------------------------------------------------------------------------

typedef unsigned short ushort_t;
typedef unsigned int uint_t;
typedef unsigned char uchar_t;
typedef __attribute__((ext_vector_type(8))) short v8s;   // 8 bf16
typedef __attribute__((ext_vector_type(4))) float v4f;   // MFMA accum
typedef __attribute__((ext_vector_type(2))) float v2f;

struct FP3 { const float* a; const float* b; const float* c; };
struct IP3 { const int* a; const int* b; const int* c; };

static __device__ __forceinline__ ushort_t f2bf(float f) {
    uint_t u = __float_as_uint(f);
    u += 0x7fffu + ((u >> 16) & 1u);   // RNE
    return (ushort_t)(u >> 16);
}
static __device__ __forceinline__ uint_t pack2(float a, float b) {
    return (uint_t)f2bf(a) | ((uint_t)f2bf(b) << 16);
}
static __device__ __forceinline__ float4 load_bf4(const ushort_t* p) {
    uint2 u = *(const uint2*)p;
    float4 f;
    f.x = __uint_as_float(u.x << 16);
    f.y = __uint_as_float(u.x & 0xffff0000u);
    f.z = __uint_as_float(u.y << 16);
    f.w = __uint_as_float(u.y & 0xffff0000u);
    return f;
}

// fp8 e4m3fn encode, RNE, clamp to +-448.
static __device__ __forceinline__ uint_t f2fp8(float f) {
    uint_t u = __float_as_uint(f);
    uint_t s = (u >> 24) & 0x80u;
    uint_t a = u & 0x7fffffffu;
    uint_t r;
    if (a >= 0x43E00000u) {            // |f| >= 448
        r = 0x7Eu;
    } else if (a < 0x3C800000u) {      // |f| < 2^-6: fp8 subnormal, unit 2^-9
        r = (uint_t)(int)rintf(__uint_as_float(a) * 512.0f);
    } else {
        uint_t t = a + 0x7FFFFu + ((a >> 20) & 1u);
        r = (t >> 20) - 960u;
        if (r > 0x7Eu) r = 0x7Eu;
    }
    return s | r;
}
static __device__ __forceinline__ float fp8f(uint_t b) {
    uint_t t = (b & 0x7Fu) << 20;
    float f = __uint_as_float(t) * 0x1.0p+120f;
    return __uint_as_float(__float_as_uint(f) | ((b & 0x80u) << 24));
}
static __device__ __forceinline__ float4 load_fp84(const uchar_t* p) {
    uint_t w = *(const uint_t*)p;
    float4 f;
#if __has_builtin(__builtin_amdgcn_cvt_pk_f32_fp8)
    v2f lo = __builtin_amdgcn_cvt_pk_f32_fp8((int)w, false);
    v2f hi = __builtin_amdgcn_cvt_pk_f32_fp8((int)w, true);
    f.x = lo[0]; f.y = lo[1]; f.z = hi[0]; f.w = hi[1];
#else
    f.x = fp8f(w & 0xffu); f.y = fp8f((w >> 8) & 0xffu);
    f.z = fp8f((w >> 16) & 0xffu); f.w = fp8f(w >> 24);
#endif
    return f;
}

// ---------------------------------------------------------------------------
__global__ __launch_bounds__(256) void zero2_k(int* a, int* b, int n) {
    int i = blockIdx.x * 256 + threadIdx.x;
    if (i < n) { a[i] = 0; b[i] = 0; }
}

// All 3 weight transposes+converts in one launch.
__global__ __launch_bounds__(256) void wt_all_k(
    const float* __restrict__ W1, const float* __restrict__ W2, const float* __restrict__ W3,
    ushort_t* __restrict__ Wt1, ushort_t* __restrict__ Wt2, ushort_t* __restrict__ Wt3) {
    int i = blockIdx.x * 256 + threadIdx.x;
    if (i < 65536) {
        int k = i >> 8, n = i & 255;
        Wt1[n * 256 + k] = f2bf(W1[i]);
    } else if (i < 98304) {
        int j = i - 65536; int k = j >> 7, n = j & 127;
        Wt2[n * 256 + k] = f2bf(W2[j]);
    } else if (i < 106496) {
        int j = i - 98304; int k = j >> 6, n = j & 63;
        Wt3[n * 128 + k] = f2bf(W3[j]);
    }
}

__global__ __launch_bounds__(256) void count_b_k(IP3 ei, int E, int Nn, int* cnt) {
    int g = blockIdx.y;
    const int* eb = g == 0 ? ei.a : (g == 1 ? ei.b : ei.c);
    int e = blockIdx.x * 256 + threadIdx.x;
    if (e < E) atomicAdd(&cnt[g * Nn + eb[E + e]], 1);
}

__global__ __launch_bounds__(256) void dis_b_k(const int* __restrict__ cnt, float* dis, int n) {
    int i = blockIdx.x * 256 + threadIdx.x;
    if (i < n) dis[i] = rsqrtf((float)cnt[i] + 1.0f);
}

// ---- 3-kernel exclusive scan over cnt[n] (chunk = 4096, <=64 chunks) ----
__global__ __launch_bounds__(256) void scan1_k(const int* __restrict__ cnt,
                                               int* __restrict__ bsums, int n) {
    int base = blockIdx.x * 4096 + threadIdx.x * 16;
    int s = 0;
    #pragma unroll
    for (int j = 0; j < 16; ++j) { int i = base + j; if (i < n) s += cnt[i]; }
    #pragma unroll
    for (int off = 32; off > 0; off >>= 1) s += __shfl_down(s, off);
    __shared__ int wsum[4];
    int lane = threadIdx.x & 63, wid = threadIdx.x >> 6;
    if (lane == 0) wsum[wid] = s;
    __syncthreads();
    if (threadIdx.x == 0) bsums[blockIdx.x] = wsum[0] + wsum[1] + wsum[2] + wsum[3];
}

__global__ __launch_bounds__(64) void scan2_k(const int* __restrict__ bsums,
                                              int* __restrict__ boffs, int nb) {
    int t = threadIdx.x;
    int v = (t < nb) ? bsums[t] : 0;
    int x = v;
    #pragma unroll
    for (int off = 1; off < 64; off <<= 1) {
        int tt = __shfl_up(x, off);
        if (t >= off) x += tt;
    }
    if (t < nb) boffs[t] = x - v;
}

__global__ __launch_bounds__(256) void scan3_k(const int* __restrict__ cnt,
                                               const int* __restrict__ boffs,
                                               int* __restrict__ rs, int n) {
    int base = blockIdx.x * 4096 + threadIdx.x * 16;
    int e[16];
    int s = 0;
    #pragma unroll
    for (int j = 0; j < 16; ++j) {
        int i = base + j;
        e[j] = (i < n) ? cnt[i] : 0;
        s += e[j];
    }
    int lane = threadIdx.x & 63, wid = threadIdx.x >> 6;
    int x = s;
    #pragma unroll
    for (int off = 1; off < 64; off <<= 1) {
        int t = __shfl_up(x, off);
        if (lane >= off) x += t;
    }
    __shared__ int wsum[4];
    if (lane == 63) wsum[wid] = x;
    __syncthreads();
    int we = 0;
    #pragma unroll
    for (int w = 0; w < 4; ++w) if (w < wid) we += wsum[w];
    int p = boffs[blockIdx.x] + we + (x - s);
    #pragma unroll
    for (int j = 0; j < 16; ++j) {
        int i = base + j;
        if (i < n) rs[i] = p;
        p += e[j];
    }
}

// csr holds LOCAL src ids (ushort, Nn < 65536); rs values absolute into 3E.
__global__ __launch_bounds__(256) void fill_b_k(IP3 ei, int E, int Nn,
    const int* __restrict__ rs, int* __restrict__ fill, ushort_t* __restrict__ csr) {
    int g = blockIdx.y;
    const int* eb = g == 0 ? ei.a : (g == 1 ? ei.b : ei.c);
    int e = blockIdx.x * 256 + threadIdx.x;
    if (e < E) {
        int d = eb[E + e];
        int gd = g * Nn + d;
        int p = atomicAdd(&fill[gd], 1);
        csr[rs[gd] + p] = (ushort_t)eb[e];
    }
}

// ---------------------------------------------------------------------------
// MFMA GEMM over M = Bc*Nn batched rows: out[m][n] = cvt((sum_k A*Wt)*dis[m])
// AFP32: A rows come from per-graph X pointers (fp32->bf16 in staging).
// OUT8: epilogue stores fp8 e4m3 instead of bf16.
// ---------------------------------------------------------------------------
template<int WM, int WN, bool AFP32, bool OUT8>
__global__ __launch_bounds__(WM * WN * 64) void gemm_mfma_k(
    FP3 xp, const ushort_t* __restrict__ Ab,
    const ushort_t* __restrict__ Wt, const float* __restrict__ dis,
    void* __restrict__ outv, int M, int K, int N, int Nn)
{
    constexpr int BM = WM * 64, BN = WN * 64, NT = WM * WN * 64;
    constexpr int LDA = 40;  // ushorts, pad breaks bank conflicts
    constexpr int STG = (BM + BN) * LDA * 2;
    constexpr int CSZ = BM * BN * (OUT8 ? 1 : 2);
    constexpr int SMEM = STG > CSZ ? STG : CSZ;
    __shared__ __align__(16) char smem[SMEM];
    ushort_t* As = (ushort_t*)smem;
    ushort_t* Bs = As + BM * LDA;

    const int tid  = threadIdx.x;
    const int lane = tid & 63;
    const int wave = tid >> 6;
    const int quad = lane >> 4, l16 = lane & 15;
    const int wm = wave / WN, wn = wave % WN;
    const int tile_m = blockIdx.y * BM, tile_n = blockIdx.x * BN;

    v4f acc[4][4];
    #pragma unroll
    for (int i = 0; i < 4; ++i)
        #pragma unroll
        for (int j = 0; j < 4; ++j)
            acc[i][j] = (v4f){0.f, 0.f, 0.f, 0.f};

    const float* Xrow = nullptr;
    int ar = 0, akc = 0;
    if constexpr (AFP32) {
        static_assert(BM * 4 == NT, "AFP32 staging assumes one chunk/thread");
        ar = tid >> 2; akc = (tid & 3) * 8;
        int gr = tile_m + ar;
        if (gr < M) {
            int lg = gr / Nn;
            int rl = gr - lg * Nn;
            const float* Xg = lg == 0 ? xp.a : (lg == 1 ? xp.b : xp.c);
            Xrow = Xg + (long)rl * K;
        }
    }

    for (int k0 = 0; k0 < K; k0 += 32) {
        if constexpr (AFP32) {
            uint4 w = make_uint4(0, 0, 0, 0);
            if (Xrow) {
                float4 f0 = *(const float4*)(Xrow + k0 + akc);
                float4 f1 = *(const float4*)(Xrow + k0 + akc + 4);
                w.x = pack2(f0.x, f0.y); w.y = pack2(f0.z, f0.w);
                w.z = pack2(f1.x, f1.y); w.w = pack2(f1.z, f1.w);
            }
            *(uint4*)&As[ar * LDA + akc] = w;
        } else {
            for (int cch = tid; cch < BM * 4; cch += NT) {
                int r = cch >> 2, kc = (cch & 3) * 8;
                int gr = tile_m + r;
                uint4 w = make_uint4(0, 0, 0, 0);
                if (gr < M) w = *(const uint4*)(Ab + (long)gr * K + k0 + kc);
                *(uint4*)&As[r * LDA + kc] = w;
            }
        }
        for (int cch = tid; cch < BN * 4; cch += NT) {
            int r = cch >> 2, kc = (cch & 3) * 8;
            uint4 w = *(const uint4*)(Wt + (long)(tile_n + r) * K + k0 + kc);
            *(uint4*)&Bs[r * LDA + kc] = w;
        }
        __syncthreads();

        v8s a[4], b[4];
        #pragma unroll
        for (int f = 0; f < 4; ++f)
            a[f] = *(const v8s*)&As[(wm * 64 + f * 16 + l16) * LDA + quad * 8];
        #pragma unroll
        for (int f = 0; f < 4; ++f)
            b[f] = *(const v8s*)&Bs[(wn * 64 + f * 16 + l16) * LDA + quad * 8];
        #pragma unroll
        for (int i = 0; i < 4; ++i)
            #pragma unroll
            for (int j = 0; j < 4; ++j)
                acc[i][j] = __builtin_amdgcn_mfma_f32_16x16x32_bf16(a[i], b[j], acc[i][j], 0, 0, 0);
        __syncthreads();
    }

    // epilogue: C/D layout col=lane&15, row=quad*4+reg; LDS round-trip.
    if constexpr (OUT8) {
        uchar_t* Cs = (uchar_t*)smem;
        #pragma unroll
        for (int i = 0; i < 4; ++i) {
            int rl0 = wm * 64 + i * 16 + quad * 4;
            #pragma unroll
            for (int r = 0; r < 4; ++r) {
                int gr = tile_m + rl0 + r;
                float s = (gr < M) ? dis[gr] : 0.f;
                #pragma unroll
                for (int j = 0; j < 4; ++j)
                    Cs[(rl0 + r) * BN + wn * 64 + j * 16 + l16] = (uchar_t)f2fp8(acc[i][j][r] * s);
            }
        }
        __syncthreads();
        uchar_t* out8 = (uchar_t*)outv;
        constexpr int CCH = BN / 8;
        for (int cch = tid; cch < BM * CCH; cch += NT) {
            int r = cch / CCH, col = (cch % CCH) * 8;
            int gr = tile_m + r;
            if (gr < M)
                *(uint2*)(out8 + (long)gr * N + col) = *(const uint2*)&Cs[r * BN + col];
        }
    } else {
        ushort_t* Cs = (ushort_t*)smem;
        #pragma unroll
        for (int i = 0; i < 4; ++i) {
            int rl0 = wm * 64 + i * 16 + quad * 4;
            #pragma unroll
            for (int r = 0; r < 4; ++r) {
                int gr = tile_m + rl0 + r;
                float s = (gr < M) ? dis[gr] : 0.f;
                #pragma unroll
                for (int j = 0; j < 4; ++j)
                    Cs[(rl0 + r) * BN + wn * 64 + j * 16 + l16] = f2bf(acc[i][j][r] * s);
            }
        }
        __syncthreads();
        ushort_t* outb = (ushort_t*)outv;
        constexpr int CCH = BN / 8;
        for (int cch = tid; cch < BM * CCH; cch += NT) {
            int r = cch / CCH, col = (cch % CCH) * 8;
            int gr = tile_m + r;
            if (gr < M)
                *(uint4*)(outb + (long)gr * N + col) = *(const uint4*)&Cs[r * BN + col];
        }
    }
}

// OUT[i] = bf16(relu(dis[i]*(H[i] + sum_nbrs H[s]) + b)); H fp8 e4m3.
template<int F>
__global__ __launch_bounds__(256) void gather_relu_k(
    const uchar_t* __restrict__ H8, ushort_t* __restrict__ OUT,
    const int* __restrict__ rs, const int* __restrict__ cnt,
    const ushort_t* __restrict__ csr, const float* __restrict__ dis,
    const float* __restrict__ bias, int n, int Nn)
{
    constexpr int L = F / 4;
    constexpr int NPB = 256 / L;
    int node = blockIdx.x * NPB + threadIdx.x / L;
    if (node >= n) return;
    int c = (threadIdx.x % L) * 4;
    int base = rs[node];
    int deg  = cnt[node];
    int lg   = node / Nn;
    if constexpr (L == 64) {  // node wave-uniform: scalarize
        base = __builtin_amdgcn_readfirstlane(base);
        deg  = __builtin_amdgcn_readfirstlane(deg);
        lg   = __builtin_amdgcn_readfirstlane(lg);
    }
    long gbase = (long)lg * Nn;

    float4 acc = load_fp84(H8 + (long)node * F + c);   // self-loop
    int k = 0;
    for (; k + 3 < deg; k += 4) {
        int s0 = csr[base + k];
        int s1 = csr[base + k + 1];
        int s2 = csr[base + k + 2];
        int s3 = csr[base + k + 3];
        float4 v0 = load_fp84(H8 + (gbase + s0) * F + c);
        float4 v1 = load_fp84(H8 + (gbase + s1) * F + c);
        float4 v2 = load_fp84(H8 + (gbase + s2) * F + c);
        float4 v3 = load_fp84(H8 + (gbase + s3) * F + c);
        acc.x += (v0.x + v1.x) + (v2.x + v3.x);
        acc.y += (v0.y + v1.y) + (v2.y + v3.y);
        acc.z += (v0.z + v1.z) + (v2.z + v3.z);
        acc.w += (v0.w + v1.w) + (v2.w + v3.w);
    }
    for (; k < deg; ++k) {
        int s0 = csr[base + k];
        float4 v0 = load_fp84(H8 + (gbase + s0) * F + c);
        acc.x += v0.x; acc.y += v0.y; acc.z += v0.z; acc.w += v0.w;
    }
    float di = dis[node];
    float4 bb = *(const float4*)(bias + c);
    ushort4 o;
    o.x = f2bf(fmaxf(fmaf(di, acc.x, bb.x), 0.f));
    o.y = f2bf(fmaxf(fmaf(di, acc.y, bb.y), 0.f));
    o.z = f2bf(fmaxf(fmaf(di, acc.z, bb.z), 0.f));
    o.w = f2bf(fmaxf(fmaf(di, acc.w, bb.w), 0.f));
    *(ushort4*)(OUT + (long)node * F + c) = o;
}

// Layer-3: gather + relu + per-block partial sum (no same-address atomics).
__global__ __launch_bounds__(256) void gather_reduce_k(
    const uchar_t* __restrict__ H8,
    const int* __restrict__ rs, const int* __restrict__ cnt,
    const ushort_t* __restrict__ csr, const float* __restrict__ dis,
    const float* __restrict__ bias, int n, int Nn, float* __restrict__ partial)
{
    constexpr int F = 64, L = 16, NPB = 16;
    int node = blockIdx.x * NPB + threadIdx.x / L;
    int c = (threadIdx.x % L) * 4;
    float val = 0.f;
    if (node < n) {
        int lg = node / Nn;
        long gbase = (long)lg * Nn;
        float4 acc = load_fp84(H8 + (long)node * F + c);
        int base = rs[node], deg = cnt[node];
        int k = 0;
        for (; k + 3 < deg; k += 4) {
            int s0 = csr[base + k];
            int s1 = csr[base + k + 1];
            int s2 = csr[base + k + 2];
            int s3 = csr[base + k + 3];
            float4 v0 = load_fp84(H8 + (gbase + s0) * F + c);
            float4 v1 = load_fp84(H8 + (gbase + s1) * F + c);
            float4 v2 = load_fp84(H8 + (gbase + s2) * F + c);
            float4 v3 = load_fp84(H8 + (gbase + s3) * F + c);
            acc.x += (v0.x + v1.x) + (v2.x + v3.x);
            acc.y += (v0.y + v1.y) + (v2.y + v3.y);
            acc.z += (v0.z + v1.z) + (v2.z + v3.z);
            acc.w += (v0.w + v1.w) + (v2.w + v3.w);
        }
        for (; k < deg; ++k) {
            int s0 = csr[base + k];
            float4 v0 = load_fp84(H8 + (gbase + s0) * F + c);
            acc.x += v0.x; acc.y += v0.y; acc.z += v0.z; acc.w += v0.w;
        }
        float di = dis[node];
        float4 bb = *(const float4*)(bias + c);
        val = fmaxf(fmaf(di, acc.x, bb.x), 0.f)
            + fmaxf(fmaf(di, acc.y, bb.y), 0.f)
            + fmaxf(fmaf(di, acc.z, bb.z), 0.f)
            + fmaxf(fmaf(di, acc.w, bb.w), 0.f);
    }
    #pragma unroll
    for (int off = 32; off > 0; off >>= 1) val += __shfl_down(val, off);
    __shared__ float wsum[4];
    int lane = threadIdx.x & 63, wid = threadIdx.x >> 6;
    if (lane == 0) wsum[wid] = val;
    __syncthreads();
    if (threadIdx.x == 0)
        partial[blockIdx.x] = wsum[0] + wsum[1] + wsum[2] + wsum[3];
}

// Sum npart partials -> out[0] = total/64. Single block.
__global__ __launch_bounds__(1024) void reduce_partials_k(
    const float* __restrict__ partial, int npart, float* __restrict__ out)
{
    float s = 0.f;
    for (int i = threadIdx.x; i < npart; i += 1024) s += partial[i];
    #pragma unroll
    for (int off = 32; off > 0; off >>= 1) s += __shfl_down(s, off);
    __shared__ float wsum[16];
    int lane = threadIdx.x & 63, wid = threadIdx.x >> 6;
    if (lane == 0) wsum[wid] = s;
    __syncthreads();
    if (threadIdx.x == 0) {
        float t = 0.f;
        #pragma unroll
        for (int w = 0; w < 16; ++w) t += wsum[w];
        out[0] = t * (1.0f / 64.0f);
    }
}

extern "C" void kernel_launch(void* const* d_in, const int* in_sizes, int n_in,
                              void* d_out, int out_size, void* d_ws, size_t ws_size,
                              hipStream_t stream) {
    const float* X[3]  = {(const float*)d_in[0], (const float*)d_in[1], (const float*)d_in[2]};
    const int*   EI[3] = {(const int*)d_in[3], (const int*)d_in[4], (const int*)d_in[5]};
    const float* W1 = (const float*)d_in[6];
    const float* b1 = (const float*)d_in[7];
    const float* W2 = (const float*)d_in[8];
    const float* b2 = (const float*)d_in[9];
    const float* W3 = (const float*)d_in[10];
    const float* b3 = (const float*)d_in[11];
    float* out = (float*)d_out;

    const int Nn = in_sizes[0] / 256;   // 50000 (< 65536 for ushort csr)
    const int E  = in_sizes[3] / 2;     // 800000
    const int B  = 3;

    // ---- workspace layout (512B-aligned regions) ----
    char* base = (char*)d_ws;
    size_t off = 0;
    auto take = [&](size_t bytes) -> void* {
        void* r = base + off;
        off += (bytes + 511) & ~(size_t)511;
        return r;
    };
    float* dis = (float*)take((size_t)B * Nn * 4);
    int* cnt   = (int*)take((size_t)B * Nn * 4);
    int* fill  = (int*)take((size_t)B * Nn * 4);
    int* rs    = (int*)take((size_t)B * Nn * 4);
    ushort_t* csr = (ushort_t*)take((size_t)B * E * 2);
    int* bsums = (int*)take(64 * 4);
    int* boffs = (int*)take(64 * 4);
    ushort_t* Wt1 = (ushort_t*)take(256 * 256 * 2);
    ushort_t* Wt2 = (ushort_t*)take(128 * 256 * 2);
    ushort_t* Wt3 = (ushort_t*)take(64 * 128 * 2);
    float* partial = (float*)take(((size_t)B * Nn / 16 + 64) * 4);
    size_t fixed = off;
    size_t abFull = ((size_t)B * Nn * 256 * 2 + 511) & ~(size_t)511;
    size_t hbFull = ((size_t)B * Nn * 256 + 511) & ~(size_t)511;
    const bool batched = ws_size >= fixed + abFull + hbFull;
    const int Bc = batched ? 3 : 1;
    ushort_t* Ab = (ushort_t*)take((size_t)Bc * Nn * 256 * 2);
    uchar_t* Hsh = (uchar_t*)take((size_t)Bc * Nn * 256);  // fp8: [.,256]/[.,128]/[.,64]

    IP3 ei = {EI[0], EI[1], EI[2]};
    const int nb_e  = (E + 255) / 256;
    const int nAll  = B * Nn;
    const int nb_sc = (nAll + 4095) / 4096;   // <= 64

    // ---- prep + batched CSR build (all 3 graphs) ----
    zero2_k<<<(nAll + 255) / 256, 256, 0, stream>>>(cnt, fill, nAll);
    wt_all_k<<<(106496 + 255) / 256, 256, 0, stream>>>(W1, W2, W3, Wt1, Wt2, Wt3);
    count_b_k<<<dim3(nb_e, 3), 256, 0, stream>>>(ei, E, Nn, cnt);
    dis_b_k<<<(nAll + 255) / 256, 256, 0, stream>>>(cnt, dis, nAll);
    scan1_k<<<nb_sc, 256, 0, stream>>>(cnt, bsums, nAll);
    scan2_k<<<1, 64, 0, stream>>>(bsums, boffs, nb_sc);
    scan3_k<<<nb_sc, 256, 0, stream>>>(cnt, boffs, rs, nAll);
    fill_b_k<<<dim3(nb_e, 3), 256, 0, stream>>>(ei, E, Nn, rs, fill, csr);

    // ---- layer pipeline (batched over Bc graphs per pass) ----
    const int Mp  = Bc * Nn;
    const int npb = (Mp + 15) / 16;            // gather_reduce blocks per pass
    for (int g0 = 0; g0 < B; g0 += Bc) {
        const int M = Mp;
        FP3 xp;
        if (Bc == 3) { xp.a = X[0]; xp.b = X[1]; xp.c = X[2]; }
        else         { xp.a = X[g0]; xp.b = X[g0]; xp.c = X[g0]; }
        const float* disl = dis + (size_t)g0 * Nn;
        const int*   rsl  = rs  + (size_t)g0 * Nn;
        const int*   cntl = cnt + (size_t)g0 * Nn;

        // L1: X fp32 [M,256] @ Wt1 -> Hsh fp8 [M,256]
        gemm_mfma_k<1, 4, true, true><<<dim3(1, (M + 63) / 64), 256, 0, stream>>>(
            xp, nullptr, Wt1, disl, Hsh, M, 256, 256, Nn);
        gather_relu_k<256><<<(M + 3) / 4, 256, 0, stream>>>(
            Hsh, Ab, rsl, cntl, csr, disl, b1, M, Nn);

        // L2: Ab bf16 [M,256] @ Wt2 -> Hsh fp8 [M,128]
        gemm_mfma_k<2, 2, false, true><<<dim3(1, (M + 127) / 128), 256, 0, stream>>>(
            xp, Ab, Wt2, disl, Hsh, M, 256, 128, Nn);
        gather_relu_k<128><<<(M + 7) / 8, 256, 0, stream>>>(
            Hsh, Ab, rsl, cntl, csr, disl, b2, M, Nn);

        // L3: Ab bf16 [M,128] @ Wt3 -> Hsh fp8 [M,64], partial reduce
        gemm_mfma_k<2, 1, false, true><<<dim3(1, (M + 127) / 128), 128, 0, stream>>>(
            xp, Ab, Wt3, disl, Hsh, M, 128, 64, Nn);
        gather_reduce_k<<<npb, 256, 0, stream>>>(
            Hsh, rsl, cntl, csr, disl, b3, M, Nn, partial + (g0 / Bc) * npb);
    }
    reduce_partials_k<<<1, 1024, 0, stream>>>(partial, (B / Bc) * npb, out);
}

// Round 7
// 692.999 us; speedup vs baseline: 22.2584x; 1.0591x over previous
//
#include <hip/hip_runtime.h>
#include <hip/hip_bf16.h>

// ---------------------------------------------------------------------------
// GCN stack: 3 graphs x 3 layers (256->256->128->64), final scalar = sum/64.
// Math: with h' = (x@W) * dis[row],
//   out[i] = relu( dis[i] * (h'[i] + sum_{e: dst=i} h'[src[e]]) + b )
// R7: (a) fill_csr in 4 dst-range passes so the csr write window stays
// L2-resident (was 146 MB of line write-throughs); (b) GEMM fp8 epilogue
// packs 4 bytes/lane and stores direct-to-global in a PERMUTED column layout
// (within each 64-col block: pos l16*4+j holds actual col j*16+l16) -- no
// LDS round-trip, no byte-write bank conflicts. Downstream consumers use
// permuted biases (b1p/b2p/b3p) and k-permuted Wt2/Wt3; the final scalar
// sum is permutation-invariant. L1 GEMM retiled to 128x256, 8 waves.
// ---------------------------------------------------------------------------

typedef unsigned short ushort_t;
typedef unsigned int uint_t;
typedef unsigned char uchar_t;
typedef __attribute__((ext_vector_type(8))) short v8s;   // 8 bf16
typedef __attribute__((ext_vector_type(4))) float v4f;   // MFMA accum
typedef __attribute__((ext_vector_type(2))) float v2f;

struct FP3 { const float* a; const float* b; const float* c; };
struct IP3 { const int* a; const int* b; const int* c; };

static __device__ __forceinline__ ushort_t f2bf(float f) {
    uint_t u = __float_as_uint(f);
    u += 0x7fffu + ((u >> 16) & 1u);   // RNE
    return (ushort_t)(u >> 16);
}
static __device__ __forceinline__ uint_t pack2(float a, float b) {
    return (uint_t)f2bf(a) | ((uint_t)f2bf(b) << 16);
}

// permutation within each 64-block: stored pos q holds actual col P64(q)
static __device__ __forceinline__ int P64(int q) {
    return (q & ~63) | (((q & 3) << 4) | ((q & 63) >> 2));
}

// fp8 e4m3fn encode, RNE, clamp (fallback path).
static __device__ __forceinline__ uint_t f2fp8(float f) {
    uint_t u = __float_as_uint(f);
    uint_t s = (u >> 24) & 0x80u;
    uint_t a = u & 0x7fffffffu;
    uint_t r;
    if (a >= 0x43E00000u) {
        r = 0x7Eu;
    } else if (a < 0x3C800000u) {
        r = (uint_t)(int)rintf(__uint_as_float(a) * 512.0f);
    } else {
        uint_t t = a + 0x7FFFFu + ((a >> 20) & 1u);
        r = (t >> 20) - 960u;
        if (r > 0x7Eu) r = 0x7Eu;
    }
    return s | r;
}
static __device__ __forceinline__ uint_t pack_fp8x4(float a, float b, float c, float d) {
#if __has_builtin(__builtin_amdgcn_cvt_pk_fp8_f32)
    int w = 0;
    w = __builtin_amdgcn_cvt_pk_fp8_f32(a, b, w, false);   // bytes 0,1
    w = __builtin_amdgcn_cvt_pk_fp8_f32(c, d, w, true);    // bytes 2,3
    return (uint_t)w;
#else
    return f2fp8(a) | (f2fp8(b) << 8) | (f2fp8(c) << 16) | (f2fp8(d) << 24);
#endif
}
static __device__ __forceinline__ float fp8f(uint_t b) {
    uint_t t = (b & 0x7Fu) << 20;
    float f = __uint_as_float(t) * 0x1.0p+120f;
    return __uint_as_float(__float_as_uint(f) | ((b & 0x80u) << 24));
}
static __device__ __forceinline__ float4 load_fp84(const uchar_t* p) {
    uint_t w = *(const uint_t*)p;
    float4 f;
#if __has_builtin(__builtin_amdgcn_cvt_pk_f32_fp8)
    v2f lo = __builtin_amdgcn_cvt_pk_f32_fp8((int)w, false);
    v2f hi = __builtin_amdgcn_cvt_pk_f32_fp8((int)w, true);
    f.x = lo[0]; f.y = lo[1]; f.z = hi[0]; f.w = hi[1];
#else
    f.x = fp8f(w & 0xffu); f.y = fp8f((w >> 8) & 0xffu);
    f.z = fp8f((w >> 16) & 0xffu); f.w = fp8f(w >> 24);
#endif
    return f;
}

// ---------------------------------------------------------------------------
__global__ __launch_bounds__(256) void zero2_k(int* a, int* b, int n) {
    int i = blockIdx.x * 256 + threadIdx.x;
    if (i < n) { a[i] = 0; b[i] = 0; }
}

// Weight transpose+convert (Wt2/Wt3 k-permuted) + permuted bias copies.
__global__ __launch_bounds__(256) void wt_all_k(
    const float* __restrict__ W1, const float* __restrict__ W2, const float* __restrict__ W3,
    const float* __restrict__ b1, const float* __restrict__ b2, const float* __restrict__ b3,
    ushort_t* __restrict__ Wt1, ushort_t* __restrict__ Wt2, ushort_t* __restrict__ Wt3,
    float* __restrict__ b1p, float* __restrict__ b2p, float* __restrict__ b3p) {
    int i = blockIdx.x * 256 + threadIdx.x;
    if (i < 65536) {
        int k = i >> 8, n = i & 255;
        Wt1[n * 256 + k] = f2bf(W1[i]);            // A of GEMM-1 (X) unpermuted
    } else if (i < 98304) {
        int j = i - 65536; int k = j >> 7, n = j & 127;   // k' in [0,256)
        Wt2[n * 256 + k] = f2bf(W2[P64(k) * 128 + n]);
    } else if (i < 106496) {
        int j = i - 98304; int k = j >> 6, n = j & 63;    // k' in [0,128)
        Wt3[n * 128 + k] = f2bf(W3[P64(k) * 64 + n]);
    } else if (i < 106752) {
        int c = i - 106496; b1p[c] = b1[P64(c)];
    } else if (i < 106880) {
        int c = i - 106752; b2p[c] = b2[P64(c)];
    } else if (i < 106944) {
        int c = i - 106880; b3p[c] = b3[P64(c)];
    }
}

__global__ __launch_bounds__(256) void count_b_k(IP3 ei, int E, int Nn, int* cnt) {
    int g = blockIdx.y;
    const int* eb = g == 0 ? ei.a : (g == 1 ? ei.b : ei.c);
    int e = blockIdx.x * 256 + threadIdx.x;
    if (e < E) atomicAdd(&cnt[g * Nn + eb[E + e]], 1);
}

__global__ __launch_bounds__(256) void dis_b_k(const int* __restrict__ cnt, float* dis, int n) {
    int i = blockIdx.x * 256 + threadIdx.x;
    if (i < n) dis[i] = rsqrtf((float)cnt[i] + 1.0f);
}

// ---- 3-kernel exclusive scan over cnt[n] (chunk = 4096, <=64 chunks) ----
__global__ __launch_bounds__(256) void scan1_k(const int* __restrict__ cnt,
                                               int* __restrict__ bsums, int n) {
    int base = blockIdx.x * 4096 + threadIdx.x * 16;
    int s = 0;
    #pragma unroll
    for (int j = 0; j < 16; ++j) { int i = base + j; if (i < n) s += cnt[i]; }
    #pragma unroll
    for (int off = 32; off > 0; off >>= 1) s += __shfl_down(s, off);
    __shared__ int wsum[4];
    int lane = threadIdx.x & 63, wid = threadIdx.x >> 6;
    if (lane == 0) wsum[wid] = s;
    __syncthreads();
    if (threadIdx.x == 0) bsums[blockIdx.x] = wsum[0] + wsum[1] + wsum[2] + wsum[3];
}

__global__ __launch_bounds__(64) void scan2_k(const int* __restrict__ bsums,
                                              int* __restrict__ boffs, int nb) {
    int t = threadIdx.x;
    int v = (t < nb) ? bsums[t] : 0;
    int x = v;
    #pragma unroll
    for (int off = 1; off < 64; off <<= 1) {
        int tt = __shfl_up(x, off);
        if (t >= off) x += tt;
    }
    if (t < nb) boffs[t] = x - v;
}

__global__ __launch_bounds__(256) void scan3_k(const int* __restrict__ cnt,
                                               const int* __restrict__ boffs,
                                               int* __restrict__ rs, int n) {
    int base = blockIdx.x * 4096 + threadIdx.x * 16;
    int e[16];
    int s = 0;
    #pragma unroll
    for (int j = 0; j < 16; ++j) {
        int i = base + j;
        e[j] = (i < n) ? cnt[i] : 0;
        s += e[j];
    }
    int lane = threadIdx.x & 63, wid = threadIdx.x >> 6;
    int x = s;
    #pragma unroll
    for (int off = 1; off < 64; off <<= 1) {
        int t = __shfl_up(x, off);
        if (lane >= off) x += t;
    }
    __shared__ int wsum[4];
    if (lane == 63) wsum[wid] = x;
    __syncthreads();
    int we = 0;
    #pragma unroll
    for (int w = 0; w < 4; ++w) if (w < wid) we += wsum[w];
    int p = boffs[blockIdx.x] + we + (x - s);
    #pragma unroll
    for (int j = 0; j < 16; ++j) {
        int i = base + j;
        if (i < n) rs[i] = p;
        p += e[j];
    }
}

// Windowed fill: pass p only writes dst in [p*W, p*W+W) so the csr write
// window stays L2-resident (kills per-store line write-through to HBM).
#define NPASS 4
__global__ __launch_bounds__(256) void fill_b_k(IP3 ei, int E, int Nn,
    const int* __restrict__ rs, int* __restrict__ fill, ushort_t* __restrict__ csr) {
    int g = blockIdx.y / NPASS, p = blockIdx.y % NPASS;
    const int* eb = g == 0 ? ei.a : (g == 1 ? ei.b : ei.c);
    int W = (Nn + NPASS - 1) / NPASS;
    int lo = p * W, hi = lo + W;
    int e = blockIdx.x * 256 + threadIdx.x;
    if (e < E) {
        int d = eb[E + e];
        if (d >= lo && d < hi) {
            int gd = g * Nn + d;
            int slot = atomicAdd(&fill[gd], 1);
            csr[rs[gd] + slot] = (ushort_t)eb[e];
        }
    }
}

// ---------------------------------------------------------------------------
// MFMA GEMM over M = Bc*Nn rows: H8[m][c'] = fp8(D[m][P64(c')] * dis[m]).
// Direct permuted global store: lane packs j=0..3 bytes into one dword at
// column base wn*64 + l16*4 (no LDS round-trip, no bank conflicts).
// ---------------------------------------------------------------------------
template<int WM, int WN, bool AFP32>
__global__ __launch_bounds__(WM * WN * 64) void gemm_mfma_k(
    FP3 xp, const ushort_t* __restrict__ Ab,
    const ushort_t* __restrict__ Wt, const float* __restrict__ dis,
    uchar_t* __restrict__ out8, int M, int K, int N, int Nn)
{
    constexpr int BM = WM * 64, BN = WN * 64, NT = WM * WN * 64;
    constexpr int LDA = 40;  // ushorts; pad breaks staging-read conflicts
    __shared__ __align__(16) ushort_t As[BM * LDA];
    __shared__ __align__(16) ushort_t Bs[BN * LDA];

    const int tid  = threadIdx.x;
    const int lane = tid & 63;
    const int wave = tid >> 6;
    const int quad = lane >> 4, l16 = lane & 15;
    const int wm = wave / WN, wn = wave % WN;
    const int tile_m = blockIdx.y * BM, tile_n = blockIdx.x * BN;

    v4f acc[4][4];
    #pragma unroll
    for (int i = 0; i < 4; ++i)
        #pragma unroll
        for (int j = 0; j < 4; ++j)
            acc[i][j] = (v4f){0.f, 0.f, 0.f, 0.f};

    const float* Xrow = nullptr;
    int ar = 0, akc = 0;
    if constexpr (AFP32) {
        static_assert(BM * 4 == NT, "AFP32 staging assumes one chunk/thread");
        ar = tid >> 2; akc = (tid & 3) * 8;
        int gr = tile_m + ar;
        if (gr < M) {
            int lg = gr / Nn;
            int rl = gr - lg * Nn;
            const float* Xg = lg == 0 ? xp.a : (lg == 1 ? xp.b : xp.c);
            Xrow = Xg + (long)rl * K;
        }
    }

    for (int k0 = 0; k0 < K; k0 += 32) {
        if constexpr (AFP32) {
            uint4 w = make_uint4(0, 0, 0, 0);
            if (Xrow) {
                float4 f0 = *(const float4*)(Xrow + k0 + akc);
                float4 f1 = *(const float4*)(Xrow + k0 + akc + 4);
                w.x = pack2(f0.x, f0.y); w.y = pack2(f0.z, f0.w);
                w.z = pack2(f1.x, f1.y); w.w = pack2(f1.z, f1.w);
            }
            *(uint4*)&As[ar * LDA + akc] = w;
        } else {
            #pragma unroll
            for (int cch = tid; cch < BM * 4; cch += NT) {
                int r = cch >> 2, kc = (cch & 3) * 8;
                int gr = tile_m + r;
                uint4 w = make_uint4(0, 0, 0, 0);
                if (gr < M) w = *(const uint4*)(Ab + (long)gr * K + k0 + kc);
                *(uint4*)&As[r * LDA + kc] = w;
            }
        }
        #pragma unroll
        for (int cch = tid; cch < BN * 4; cch += NT) {
            int r = cch >> 2, kc = (cch & 3) * 8;
            uint4 w = *(const uint4*)(Wt + (long)(tile_n + r) * K + k0 + kc);
            *(uint4*)&Bs[r * LDA + kc] = w;
        }
        __syncthreads();

        v8s a[4], b[4];
        #pragma unroll
        for (int f = 0; f < 4; ++f)
            a[f] = *(const v8s*)&As[(wm * 64 + f * 16 + l16) * LDA + quad * 8];
        #pragma unroll
        for (int f = 0; f < 4; ++f)
            b[f] = *(const v8s*)&Bs[(wn * 64 + f * 16 + l16) * LDA + quad * 8];
        #pragma unroll
        for (int i = 0; i < 4; ++i)
            #pragma unroll
            for (int j = 0; j < 4; ++j)
                acc[i][j] = __builtin_amdgcn_mfma_f32_16x16x32_bf16(a[i], b[j], acc[i][j], 0, 0, 0);
        __syncthreads();
    }

    // direct permuted fp8 epilogue (C/D: col=lane&15, row=quad*4+reg)
    #pragma unroll
    for (int i = 0; i < 4; ++i) {
        #pragma unroll
        for (int r = 0; r < 4; ++r) {
            int gr = tile_m + wm * 64 + i * 16 + quad * 4 + r;
            if (gr < M) {
                float s = dis[gr];
                uint_t w = pack_fp8x4(acc[i][0][r] * s, acc[i][1][r] * s,
                                      acc[i][2][r] * s, acc[i][3][r] * s);
                *(uint_t*)(out8 + (long)gr * N + tile_n + wn * 64 + l16 * 4) = w;
            }
        }
    }
}

// OUT[i] = bf16(relu(dis[i]*(H[i] + sum_nbrs H[s]) + bp)); H fp8, cols permuted
// (bp pre-permuted to match). OUT inherits the permuted order.
template<int F>
__global__ __launch_bounds__(256) void gather_relu_k(
    const uchar_t* __restrict__ H8, ushort_t* __restrict__ OUT,
    const int* __restrict__ rs, const int* __restrict__ cnt,
    const ushort_t* __restrict__ csr, const float* __restrict__ dis,
    const float* __restrict__ bias, int n, int Nn)
{
    constexpr int L = F / 4;
    constexpr int NPB = 256 / L;
    int node = blockIdx.x * NPB + threadIdx.x / L;
    if (node >= n) return;
    int c = (threadIdx.x % L) * 4;
    int base = rs[node];
    int deg  = cnt[node];
    int lg   = node / Nn;
    if constexpr (L == 64) {  // node wave-uniform: scalarize
        base = __builtin_amdgcn_readfirstlane(base);
        deg  = __builtin_amdgcn_readfirstlane(deg);
        lg   = __builtin_amdgcn_readfirstlane(lg);
    }
    long gbase = (long)lg * Nn;

    float4 acc = load_fp84(H8 + (long)node * F + c);   // self-loop
    int k = 0;
    for (; k + 3 < deg; k += 4) {
        int s0 = csr[base + k];
        int s1 = csr[base + k + 1];
        int s2 = csr[base + k + 2];
        int s3 = csr[base + k + 3];
        float4 v0 = load_fp84(H8 + (gbase + s0) * F + c);
        float4 v1 = load_fp84(H8 + (gbase + s1) * F + c);
        float4 v2 = load_fp84(H8 + (gbase + s2) * F + c);
        float4 v3 = load_fp84(H8 + (gbase + s3) * F + c);
        acc.x += (v0.x + v1.x) + (v2.x + v3.x);
        acc.y += (v0.y + v1.y) + (v2.y + v3.y);
        acc.z += (v0.z + v1.z) + (v2.z + v3.z);
        acc.w += (v0.w + v1.w) + (v2.w + v3.w);
    }
    for (; k < deg; ++k) {
        int s0 = csr[base + k];
        float4 v0 = load_fp84(H8 + (gbase + s0) * F + c);
        acc.x += v0.x; acc.y += v0.y; acc.z += v0.z; acc.w += v0.w;
    }
    float di = dis[node];
    float4 bb = *(const float4*)(bias + c);
    ushort4 o;
    o.x = f2bf(fmaxf(fmaf(di, acc.x, bb.x), 0.f));
    o.y = f2bf(fmaxf(fmaf(di, acc.y, bb.y), 0.f));
    o.z = f2bf(fmaxf(fmaf(di, acc.z, bb.z), 0.f));
    o.w = f2bf(fmaxf(fmaf(di, acc.w, bb.w), 0.f));
    *(ushort4*)(OUT + (long)node * F + c) = o;
}

// Layer-3: gather + relu + per-block partial sum (permutation-invariant).
__global__ __launch_bounds__(256) void gather_reduce_k(
    const uchar_t* __restrict__ H8,
    const int* __restrict__ rs, const int* __restrict__ cnt,
    const ushort_t* __restrict__ csr, const float* __restrict__ dis,
    const float* __restrict__ bias, int n, int Nn, float* __restrict__ partial)
{
    constexpr int F = 64, L = 16, NPB = 16;
    int node = blockIdx.x * NPB + threadIdx.x / L;
    int c = (threadIdx.x % L) * 4;
    float val = 0.f;
    if (node < n) {
        int lg = node / Nn;
        long gbase = (long)lg * Nn;
        float4 acc = load_fp84(H8 + (long)node * F + c);
        int base = rs[node], deg = cnt[node];
        int k = 0;
        for (; k + 3 < deg; k += 4) {
            int s0 = csr[base + k];
            int s1 = csr[base + k + 1];
            int s2 = csr[base + k + 2];
            int s3 = csr[base + k + 3];
            float4 v0 = load_fp84(H8 + (gbase + s0) * F + c);
            float4 v1 = load_fp84(H8 + (gbase + s1) * F + c);
            float4 v2 = load_fp84(H8 + (gbase + s2) * F + c);
            float4 v3 = load_fp84(H8 + (gbase + s3) * F + c);
            acc.x += (v0.x + v1.x) + (v2.x + v3.x);
            acc.y += (v0.y + v1.y) + (v2.y + v3.y);
            acc.z += (v0.z + v1.z) + (v2.z + v3.z);
            acc.w += (v0.w + v1.w) + (v2.w + v3.w);
        }
        for (; k < deg; ++k) {
            int s0 = csr[base + k];
            float4 v0 = load_fp84(H8 + (gbase + s0) * F + c);
            acc.x += v0.x; acc.y += v0.y; acc.z += v0.z; acc.w += v0.w;
        }
        float di = dis[node];
        float4 bb = *(const float4*)(bias + c);
        val = fmaxf(fmaf(di, acc.x, bb.x), 0.f)
            + fmaxf(fmaf(di, acc.y, bb.y), 0.f)
            + fmaxf(fmaf(di, acc.z, bb.z), 0.f)
            + fmaxf(fmaf(di, acc.w, bb.w), 0.f);
    }
    #pragma unroll
    for (int off = 32; off > 0; off >>= 1) val += __shfl_down(val, off);
    __shared__ float wsum[4];
    int lane = threadIdx.x & 63, wid = threadIdx.x >> 6;
    if (lane == 0) wsum[wid] = val;
    __syncthreads();
    if (threadIdx.x == 0)
        partial[blockIdx.x] = wsum[0] + wsum[1] + wsum[2] + wsum[3];
}

__global__ __launch_bounds__(1024) void reduce_partials_k(
    const float* __restrict__ partial, int npart, float* __restrict__ out)
{
    float s = 0.f;
    for (int i = threadIdx.x; i < npart; i += 1024) s += partial[i];
    #pragma unroll
    for (int off = 32; off > 0; off >>= 1) s += __shfl_down(s, off);
    __shared__ float wsum[16];
    int lane = threadIdx.x & 63, wid = threadIdx.x >> 6;
    if (lane == 0) wsum[wid] = s;
    __syncthreads();
    if (threadIdx.x == 0) {
        float t = 0.f;
        #pragma unroll
        for (int w = 0; w < 16; ++w) t += wsum[w];
        out[0] = t * (1.0f / 64.0f);
    }
}

extern "C" void kernel_launch(void* const* d_in, const int* in_sizes, int n_in,
                              void* d_out, int out_size, void* d_ws, size_t ws_size,
                              hipStream_t stream) {
    const float* X[3]  = {(const float*)d_in[0], (const float*)d_in[1], (const float*)d_in[2]};
    const int*   EI[3] = {(const int*)d_in[3], (const int*)d_in[4], (const int*)d_in[5]};
    const float* W1 = (const float*)d_in[6];
    const float* b1 = (const float*)d_in[7];
    const float* W2 = (const float*)d_in[8];
    const float* b2 = (const float*)d_in[9];
    const float* W3 = (const float*)d_in[10];
    const float* b3 = (const float*)d_in[11];
    float* out = (float*)d_out;

    const int Nn = in_sizes[0] / 256;   // 50000 (< 65536 for ushort csr)
    const int E  = in_sizes[3] / 2;     // 800000
    const int B  = 3;

    // ---- workspace layout (512B-aligned regions) ----
    char* base = (char*)d_ws;
    size_t off = 0;
    auto take = [&](size_t bytes) -> void* {
        void* r = base + off;
        off += (bytes + 511) & ~(size_t)511;
        return r;
    };
    float* dis = (float*)take((size_t)B * Nn * 4);
    int* cnt   = (int*)take((size_t)B * Nn * 4);
    int* fill  = (int*)take((size_t)B * Nn * 4);
    int* rs    = (int*)take((size_t)B * Nn * 4);
    ushort_t* csr = (ushort_t*)take((size_t)B * E * 2);
    int* bsums = (int*)take(64 * 4);
    int* boffs = (int*)take(64 * 4);
    ushort_t* Wt1 = (ushort_t*)take(256 * 256 * 2);
    ushort_t* Wt2 = (ushort_t*)take(128 * 256 * 2);
    ushort_t* Wt3 = (ushort_t*)take(64 * 128 * 2);
    float* b1p = (float*)take(256 * 4);
    float* b2p = (float*)take(128 * 4);
    float* b3p = (float*)take(64 * 4);
    float* partial = (float*)take(((size_t)B * Nn / 16 + 64) * 4);
    size_t fixed = off;
    size_t abFull = ((size_t)B * Nn * 256 * 2 + 511) & ~(size_t)511;
    size_t hbFull = ((size_t)B * Nn * 256 + 511) & ~(size_t)511;
    const bool batched = ws_size >= fixed + abFull + hbFull;
    const int Bc = batched ? 3 : 1;
    ushort_t* Ab = (ushort_t*)take((size_t)Bc * Nn * 256 * 2);
    uchar_t* Hsh = (uchar_t*)take((size_t)Bc * Nn * 256);  // fp8: [.,256]/[.,128]/[.,64]

    IP3 ei = {EI[0], EI[1], EI[2]};
    const int nb_e  = (E + 255) / 256;
    const int nAll  = B * Nn;
    const int nb_sc = (nAll + 4095) / 4096;   // <= 64

    // ---- prep + batched CSR build (all 3 graphs) ----
    zero2_k<<<(nAll + 255) / 256, 256, 0, stream>>>(cnt, fill, nAll);
    wt_all_k<<<(106944 + 255) / 256, 256, 0, stream>>>(
        W1, W2, W3, b1, b2, b3, Wt1, Wt2, Wt3, b1p, b2p, b3p);
    count_b_k<<<dim3(nb_e, 3), 256, 0, stream>>>(ei, E, Nn, cnt);
    dis_b_k<<<(nAll + 255) / 256, 256, 0, stream>>>(cnt, dis, nAll);
    scan1_k<<<nb_sc, 256, 0, stream>>>(cnt, bsums, nAll);
    scan2_k<<<1, 64, 0, stream>>>(bsums, boffs, nb_sc);
    scan3_k<<<nb_sc, 256, 0, stream>>>(cnt, boffs, rs, nAll);
    fill_b_k<<<dim3(nb_e, 3 * NPASS), 256, 0, stream>>>(ei, E, Nn, rs, fill, csr);

    // ---- layer pipeline (batched over Bc graphs per pass) ----
    const int Mp  = Bc * Nn;
    const int npb = (Mp + 15) / 16;            // gather_reduce blocks per pass
    for (int g0 = 0; g0 < B; g0 += Bc) {
        const int M = Mp;
        FP3 xp;
        if (Bc == 3) { xp.a = X[0]; xp.b = X[1]; xp.c = X[2]; }
        else         { xp.a = X[g0]; xp.b = X[g0]; xp.c = X[g0]; }
        const float* disl = dis + (size_t)g0 * Nn;
        const int*   rsl  = rs  + (size_t)g0 * Nn;
        const int*   cntl = cnt + (size_t)g0 * Nn;

        // L1: X fp32 [M,256] @ Wt1 -> Hsh fp8 [M,256] (permuted cols)
        gemm_mfma_k<2, 4, true><<<dim3(1, (M + 127) / 128), 512, 0, stream>>>(
            xp, nullptr, Wt1, disl, Hsh, M, 256, 256, Nn);
        gather_relu_k<256><<<(M + 3) / 4, 256, 0, stream>>>(
            Hsh, Ab, rsl, cntl, csr, disl, b1p, M, Nn);

        // L2: Ab bf16 [M,256](perm) @ Wt2(perm-k) -> Hsh fp8 [M,128](perm)
        gemm_mfma_k<2, 2, false><<<dim3(1, (M + 127) / 128), 256, 0, stream>>>(
            xp, Ab, Wt2, disl, Hsh, M, 256, 128, Nn);
        gather_relu_k<128><<<(M + 7) / 8, 256, 0, stream>>>(
            Hsh, Ab, rsl, cntl, csr, disl, b2p, M, Nn);

        // L3: Ab bf16 [M,128](perm) @ Wt3(perm-k) -> Hsh fp8 [M,64](perm)
        gemm_mfma_k<2, 1, false><<<dim3(1, (M + 127) / 128), 128, 0, stream>>>(
            xp, Ab, Wt3, disl, Hsh, M, 128, 64, Nn);
        gather_reduce_k<<<npb, 256, 0, stream>>>(
            Hsh, rsl, cntl, csr, disl, b3p, M, Nn, partial + (g0 / Bc) * npb);
    }
    reduce_partials_k<<<1, 1024, 0, stream>>>(partial, (B / Bc) * npb, out);
}